// Round 14
// baseline (315.612 us; speedup 1.0000x reference)
//
#include <hip/hip_runtime.h>
#include <hip/hip_fp16.h>
#include <math.h>

#define N_NODES 100000
#define N_EDGES 1600000
#define F_IN 8
#define HID 32
#define HEADS 4
#define F1 128    // HEADS*HID
#define F2 16     // OUT
#define NBLK_SC 6250    // scatter blocks: 1 edge per thread (6250*256 = 1.6M)
#define NBLK_A 391      // xa blocks of 256 nodes
#define KSLOT 64        // per-node edge capacity (mean 16, sd 4 -> 12 sigma)

__device__ __forceinline__ float leaky(float x){ return x > 0.f ? x : 0.2f * x; }
__device__ __forceinline__ float elu1(float x){ return x > 0.f ? x : __expf(x) - 1.f; }
__device__ __forceinline__ float half_of(float v, int hi){
    float2 f = __half22float2(*(__half2*)&v);
    return hi ? f.y : f.x;
}
__device__ __forceinline__ float2 h2f2(float v){ return __half22float2(*(__half2*)&v); }

// ---------------- Fused: direct edge scatter (blocks 0..6249) + xa build (rest) ----------------
// Round-13/14: the two-pass bucket/CSR build (binning at VALUBusy 2.2% +
// k_local_csr) is replaced by ONE fixed-stride scatter: eslot[d][64] blocks are
// 256 B aligned; pos = atomicAdd(&deg[d],1); 25K waves of pure TLP hide the
// atomic latency; a node's ~16 live slots span exactly one 64 B line, so the agg
// kernels' fetch pattern is unchanged. No barriers, no ordering, no second pass.
// xa16[n][8 dwords] = { x[0:8] as 4xhalf2, a_s1[0:4] as 2xhalf2, a_d1[0:4] as 2xhalf2 }
__global__ __launch_bounds__(256) void k_scatter_xa(
    const int* __restrict__ src, const int* __restrict__ dst,
    int* __restrict__ deg, int* __restrict__ eslot,
    const float* __restrict__ x, const float* __restrict__ W1,
    const float* __restrict__ as1w, const float* __restrict__ ad1w,
    float* __restrict__ xa){
    int t = threadIdx.x;
    if (blockIdx.x < NBLK_SC){
        int e = blockIdx.x * 256 + t;          // exactly N_EDGES threads
        if (e < N_EDGES){
            int d = dst[e], s = src[e];
            int pos = atomicAdd(&deg[d], 1);
            if (pos < KSLOT) eslot[((size_t)d << 6) + pos] = s;
        }
    } else {
        // ---- attention dots: c = W1·att (tiny), then fp16 xa row per node ----
        __shared__ float smem[1344];
        float* W1s  = smem;          // 1024
        float* atts = smem + 1024;   // 128
        float* attd = smem + 1152;   // 128
        float* cs   = smem + 1280;   // 32  (cs[h*8+m])
        float* cd   = smem + 1312;   // 32
        ((float4*)W1s)[t] = ((const float4*)W1)[t];
        if (t < 128){ atts[t] = as1w[t]; attd[t] = ad1w[t]; }
        __syncthreads();
        if (t < 64){
            int m = t & 7, h = (t >> 3) & 3;
            bool sel = t >= 32;
            const float* wrow = W1s + m * F1 + h * 32;
            const float* av   = (sel ? attd : atts) + h * 32;
            float s = 0.f;
            #pragma unroll
            for (int d = 0; d < 32; d++) s += wrow[d] * av[d];
            (sel ? cd : cs)[h * 8 + m] = s;
        }
        __syncthreads();
        int n = (blockIdx.x - NBLK_SC) * 256 + t;
        if (n < N_NODES){
            float4 x0 = ((const float4*)x)[n * 2];
            float4 x1 = ((const float4*)x)[n * 2 + 1];
            float4 osv, odv;
            float* po = (float*)&osv;
            float* pd = (float*)&odv;
            #pragma unroll
            for (int h = 0; h < 4; h++){
                const float* c0 = cs + h * 8;
                const float* c1 = cd + h * 8;
                po[h] = x0.x*c0[0] + x0.y*c0[1] + x0.z*c0[2] + x0.w*c0[3]
                      + x1.x*c0[4] + x1.y*c0[5] + x1.z*c0[6] + x1.w*c0[7];
                pd[h] = x0.x*c1[0] + x0.y*c1[1] + x0.z*c1[2] + x0.w*c1[3]
                      + x1.x*c1[4] + x1.y*c1[5] + x1.z*c1[6] + x1.w*c1[7];
            }
            __half2 h8[8];
            h8[0] = __floats2half2_rn(x0.x, x0.y);
            h8[1] = __floats2half2_rn(x0.z, x0.w);
            h8[2] = __floats2half2_rn(x1.x, x1.y);
            h8[3] = __floats2half2_rn(x1.z, x1.w);
            h8[4] = __floats2half2_rn(osv.x, osv.y);
            h8[5] = __floats2half2_rn(osv.z, osv.w);
            h8[6] = __floats2half2_rn(odv.x, odv.y);
            h8[7] = __floats2half2_rn(odv.z, odv.w);
            float* px = xa + (size_t)n * 8;
            *(float4*)(px)     = *(float4*)(h8);
            *(float4*)(px + 4) = *(float4*)(h8 + 4);
        }
    }
}

// ---------------- Layer 1 aggregate (x-space, fp16 rows): 8 groups x 8 lanes ----------------
// Lane l loads dword l of the 32 B row (8 lanes = one full row, <=1 line/edge).
// Lane owns head hd=l>>1 and x-dims 4(l&1)..+3 (4 fp32 accumulators).
// Edge list is eslot[n*64 + 0..deg[n]) (fixed stride, no row_ptr).
__global__ __launch_bounds__(256) void k_agg1(
    const float* __restrict__ xa, const int* __restrict__ deg, const int* __restrict__ eslot,
    float* __restrict__ xagg, float* __restrict__ dden){
    int t = threadIdx.x;
    int wv = t >> 6, lane = t & 63;
    int n = blockIdx.x * 4 + wv;               // N divisible by 4
    int g = lane >> 3;                          // edge subgroup (0..7)
    int l = lane & 7;
    int hd = l >> 1;                            // head (0..3)
    int ha = 4 + (hd >> 1), hb = hd & 1;        // a_s1[hd] lives in dword ha, half hb
    int xd = 2 * (l & 1);                       // my x dwords: xd, xd+1

    float vn = xa[(size_t)n * 8 + l];
    float adh = half_of(__shfl(vn, ha + 2, 8), hb);   // a_d1[hd]: dword 6+(hd>>1)

    float den = 0.f, ac0 = 0.f, ac1 = 0.f, ac2 = 0.f, ac3 = 0.f;
    if (g == 0){
        // self-loop (softmax shift m=0; logits O(1), fp32 acc)
        float w = __expf(leaky(half_of(__shfl(vn, ha, 8), hb) + adh));
        den = w;
        float2 p01 = h2f2(__shfl(vn, xd, 8));
        float2 p23 = h2f2(__shfl(vn, xd + 1, 8));
        ac0 = w * p01.x; ac1 = w * p01.y; ac2 = w * p23.x; ac3 = w * p23.y;
    }
    int len = deg[n]; if (len > KSLOT) len = KSLOT;
    const int* eb = eslot + ((size_t)n << 6);
    int chunk = (len + 7) >> 3;
    int i = g * chunk;
    int e = i + chunk; if (e > len) e = len;
    for (int base = i; base < e; base += 4){
        bool b1v = base + 1 < e, b2v = base + 2 < e, b3v = base + 3 < e;
        int s0 = eb[base];
        int s1 = b1v ? eb[base + 1] : s0;
        int s2 = b2v ? eb[base + 2] : s0;
        int s3 = b3v ? eb[base + 3] : s0;
        float v0 = xa[(size_t)s0 * 8 + l];
        float v1 = xa[(size_t)s1 * 8 + l];
        float v2 = xa[(size_t)s2 * 8 + l];
        float v3 = xa[(size_t)s3 * 8 + l];
        float w0 = __expf(leaky(half_of(__shfl(v0, ha, 8), hb) + adh));
        float w1 = b1v ? __expf(leaky(half_of(__shfl(v1, ha, 8), hb) + adh)) : 0.f;
        float w2 = b2v ? __expf(leaky(half_of(__shfl(v2, ha, 8), hb) + adh)) : 0.f;
        float w3 = b3v ? __expf(leaky(half_of(__shfl(v3, ha, 8), hb) + adh)) : 0.f;
        den += (w0 + w1) + (w2 + w3);
        float2 a01, a23;
        a01 = h2f2(__shfl(v0, xd, 8)); a23 = h2f2(__shfl(v0, xd + 1, 8));
        ac0 = fmaf(w0, a01.x, ac0); ac1 = fmaf(w0, a01.y, ac1);
        ac2 = fmaf(w0, a23.x, ac2); ac3 = fmaf(w0, a23.y, ac3);
        a01 = h2f2(__shfl(v1, xd, 8)); a23 = h2f2(__shfl(v1, xd + 1, 8));
        ac0 = fmaf(w1, a01.x, ac0); ac1 = fmaf(w1, a01.y, ac1);
        ac2 = fmaf(w1, a23.x, ac2); ac3 = fmaf(w1, a23.y, ac3);
        a01 = h2f2(__shfl(v2, xd, 8)); a23 = h2f2(__shfl(v2, xd + 1, 8));
        ac0 = fmaf(w2, a01.x, ac0); ac1 = fmaf(w2, a01.y, ac1);
        ac2 = fmaf(w2, a23.x, ac2); ac3 = fmaf(w2, a23.y, ac3);
        a01 = h2f2(__shfl(v3, xd, 8)); a23 = h2f2(__shfl(v3, xd + 1, 8));
        ac0 = fmaf(w3, a01.x, ac0); ac1 = fmaf(w3, a01.y, ac1);
        ac2 = fmaf(w3, a23.x, ac2); ac3 = fmaf(w3, a23.y, ac3);
    }
    // combine the eight edge-groups (lanes xor8/xor16/xor32 share l)
    den += __shfl_xor(den, 8); den += __shfl_xor(den, 16); den += __shfl_xor(den, 32);
    ac0 += __shfl_xor(ac0, 8); ac0 += __shfl_xor(ac0, 16); ac0 += __shfl_xor(ac0, 32);
    ac1 += __shfl_xor(ac1, 8); ac1 += __shfl_xor(ac1, 16); ac1 += __shfl_xor(ac1, 32);
    ac2 += __shfl_xor(ac2, 8); ac2 += __shfl_xor(ac2, 16); ac2 += __shfl_xor(ac2, 32);
    ac3 += __shfl_xor(ac3, 8); ac3 += __shfl_xor(ac3, 16); ac3 += __shfl_xor(ac3, 32);

    if (lane < 8){
        // xagg[n][hd*8 + (l&1)*4 ..+3] == xagg[n][4l..4l+3]: 8 lanes -> 128 B coalesced
        float4 o; o.x = ac0; o.y = ac1; o.z = ac2; o.w = ac3;
        *(float4*)(xagg + (size_t)n * 32 + 4 * l) = o;
        if (!(l & 1)) dden[(size_t)n * 4 + hd] = den;
    }
}

// ---------------- Dense epilogue (fp16-packed LDS, round-8 proven) ----------------
// hL1 = elu(xagg@W1/den + b1); h2 = hL1@W2. 16 nodes x 16 threads per block.
__global__ __launch_bounds__(256) void k_epi(
    const float* __restrict__ xagg, const float* __restrict__ dden,
    const float* __restrict__ W1, const float* __restrict__ W2,
    const float* __restrict__ b1, const float* __restrict__ as2w, const float* __restrict__ ad2w,
    __half* __restrict__ h2h, float* __restrict__ a_s2, float* __restrict__ a_d2){
    __shared__ __half2 W1h[F_IN * 64];   // 2 KB
    __shared__ __half2 W2t[F2 * 64];     // 4 KB, swizzled
    __shared__ __half2 hlsh[16 * 68];    // 4.25 KB
    int t = threadIdx.x;
    {
        // W1h: thread t covers W1 elems 4t..4t+3 -> m = t>>5, dim-pairs (2t)&63, +1
        float4 w1v = ((const float4*)W1)[t];
        int m = t >> 5, j = (2 * t) & 63;
        W1h[m * 64 + j]     = __floats2half2_rn(w1v.x, w1v.y);
        W1h[m * 64 + j + 1] = __floats2half2_rn(w1v.z, w1v.w);
        // W2t: transpose-scatter two float4s (one-time half-granular writes)
        #pragma unroll
        for (int hf = 0; hf < 2; hf++){
            int p = t + hf * 256;
            float4 wv = ((const float4*)W2)[p];
            int k = p >> 2, dbase = (p & 3) * 4;
            float vals[4] = {wv.x, wv.y, wv.z, wv.w};
            #pragma unroll
            for (int c = 0; c < 4; c++){
                int dw = (dbase + c) * 64 + (k >> 1);
                int sdw = dw ^ (((dw >> 6) & 7) << 2);
                ((__half*)W2t)[2 * sdw + (k & 1)] = __float2half(vals[c]);
            }
        }
    }
    __syncthreads();

    int nn = t >> 4, q = t & 15;
    int n = blockIdx.x * 16 + nn;              // N divisible by 16
    int hd = q >> 2;

    // ---- phase 1: hL1 dims 8q..8q+7 ----
    const float* xg = xagg + (size_t)n * 32 + hd * 8;
    float4 xga = *(const float4*)(xg);
    float4 xgb = *(const float4*)(xg + 4);
    float invd = 1.f / dden[(size_t)n * 4 + hd];
    float xv[8] = {xga.x, xga.y, xga.z, xga.w, xgb.x, xgb.y, xgb.z, xgb.w};
    float pre[8] = {0,0,0,0,0,0,0,0};
    #pragma unroll
    for (int m = 0; m < 8; m++){
        float4 raw = *(const float4*)(W1h + m * 64 + 4 * q);   // conflict-free: q-consecutive
        const __half2* wp = (const __half2*)&raw;
        float xm = xv[m];
        float2 f0 = __half22float2(wp[0]);
        float2 f1 = __half22float2(wp[1]);
        float2 f2 = __half22float2(wp[2]);
        float2 f3 = __half22float2(wp[3]);
        pre[0] = fmaf(xm, f0.x, pre[0]); pre[1] = fmaf(xm, f0.y, pre[1]);
        pre[2] = fmaf(xm, f1.x, pre[2]); pre[3] = fmaf(xm, f1.y, pre[3]);
        pre[4] = fmaf(xm, f2.x, pre[4]); pre[5] = fmaf(xm, f2.y, pre[5]);
        pre[6] = fmaf(xm, f3.x, pre[6]); pre[7] = fmaf(xm, f3.y, pre[7]);
    }
    float4 ba = *(const float4*)(b1 + 8 * q);
    float4 bb = *(const float4*)(b1 + 8 * q + 4);
    __half2 hout[4];
    hout[0] = __floats2half2_rn(elu1(pre[0] * invd + ba.x), elu1(pre[1] * invd + ba.y));
    hout[1] = __floats2half2_rn(elu1(pre[2] * invd + ba.z), elu1(pre[3] * invd + ba.w));
    hout[2] = __floats2half2_rn(elu1(pre[4] * invd + bb.x), elu1(pre[5] * invd + bb.y));
    hout[3] = __floats2half2_rn(elu1(pre[6] * invd + bb.z), elu1(pre[7] * invd + bb.w));
    *(float4*)(hlsh + nn * 68 + 4 * q) = *(float4*)hout;
    __syncthreads();

    // ---- phase 2: h2[n][q] = hL1 . W2col(q), fp16 packed, f32 flush every 8 terms ----
    float dot = 0.f;
    #pragma unroll
    for (int ob = 0; ob < 8; ob++){
        __half2 acc2 = __float2half2_rn(0.f);
        #pragma unroll
        for (int kb = ob * 2; kb < ob * 2 + 2; kb++){
            float4 hr = *(const float4*)(hlsh + nn * 68 + 4 * kb);
            int dwb = 64 * q + 4 * kb;
            float4 wr = *(const float4*)(W2t + (dwb ^ (((dwb >> 6) & 7) << 2)));
            const __half2* hp  = (const __half2*)&hr;
            const __half2* wp2 = (const __half2*)&wr;
            acc2 = __hfma2(hp[0], wp2[0], acc2);
            acc2 = __hfma2(hp[1], wp2[1], acc2);
            acc2 = __hfma2(hp[2], wp2[2], acc2);
            acc2 = __hfma2(hp[3], wp2[3], acc2);
        }
        float2 fa = __half22float2(acc2);
        dot += fa.x + fa.y;
    }
    float ps = dot * as2w[q];
    float pd = dot * ad2w[q];
    #pragma unroll
    for (int off = 8; off >= 1; off >>= 1){
        ps += __shfl_down(ps, off, 16);
        pd += __shfl_down(pd, off, 16);
    }
    if (q == 0){ a_s2[n] = ps; a_d2[n] = pd; }
    h2h[(size_t)n * F2 + q] = __float2half(dot);
}

// ---------------- Layer 2 aggregate (round-8 proven loop; eslot addressing) ----------------
__global__ __launch_bounds__(256) void k_agg2(
    const __half* __restrict__ h2h, const float* __restrict__ a_s2, const float* __restrict__ a_d2,
    const int* __restrict__ deg, const int* __restrict__ eslot,
    const float* __restrict__ b2, float* __restrict__ out){
    int t = threadIdx.x;
    int wv = t >> 6, lane = t & 63;
    int n = blockIdx.x * 4 + wv;       // N divisible by 4
    int g = lane >> 3;                 // edge subgroup (0..7)
    int l = lane & 7;                  // owns dims 2l, 2l+1
    float adn = a_d2[n];
    const __half* hb2 = h2h + 2 * l;

    float den = 0.f, acc0 = 0.f, acc1 = 0.f;
    if (g == 0){
        float w = __expf(leaky(a_s2[n] + adn));
        den = w;
        float2 f = __half22float2(*(const __half2*)(hb2 + ((unsigned)n << 4)));
        acc0 = w * f.x; acc1 = w * f.y;
    }
    int len = deg[n]; if (len > KSLOT) len = KSLOT;
    const int* eb = eslot + ((size_t)n << 6);
    int chunk = (len + 7) >> 3;
    int i = g * chunk;
    int e = i + chunk; if (e > len) e = len;
    for (int base = i; base < e; base += 4){
        bool v1 = base + 1 < e, v2 = base + 2 < e, v3 = base + 3 < e;
        int s0 = eb[base];
        int s1 = v1 ? eb[base + 1] : s0;
        int s2 = v2 ? eb[base + 2] : s0;
        int s3 = v3 ? eb[base + 3] : s0;
        float a0 = a_s2[s0], a1 = a_s2[s1], a2 = a_s2[s2], a3 = a_s2[s3];
        __half2 p0 = *(const __half2*)(hb2 + ((unsigned)s0 << 4));
        __half2 p1 = *(const __half2*)(hb2 + ((unsigned)s1 << 4));
        __half2 p2 = *(const __half2*)(hb2 + ((unsigned)s2 << 4));
        __half2 p3 = *(const __half2*)(hb2 + ((unsigned)s3 << 4));
        float w0 = __expf(leaky(a0 + adn));
        float w1 = v1 ? __expf(leaky(a1 + adn)) : 0.f;
        float w2 = v2 ? __expf(leaky(a2 + adn)) : 0.f;
        float w3 = v3 ? __expf(leaky(a3 + adn)) : 0.f;
        den += (w0 + w1) + (w2 + w3);
        float2 f0 = __half22float2(p0), f1 = __half22float2(p1);
        float2 f2 = __half22float2(p2), f3 = __half22float2(p3);
        acc0 += w0 * f0.x + w1 * f1.x + w2 * f2.x + w3 * f3.x;
        acc1 += w0 * f0.y + w1 * f1.y + w2 * f2.y + w3 * f3.y;
    }
    #pragma unroll
    for (int off = 8; off <= 32; off <<= 1){
        den  += __shfl_xor(den, off);
        acc0 += __shfl_xor(acc0, off);
        acc1 += __shfl_xor(acc1, off);
    }
    if (g == 0){
        float inv = 1.f / (den + 1e-16f);
        float e0v = elu1(acc0 * inv + b2[2 * l]);
        float e1v = elu1(acc1 * inv + b2[2 * l + 1]);
        float2 ov; ov.x = e0v; ov.y = e1v;
        *(float2*)(out + (size_t)n * 16 + 2 * l) = ov;
    }
}

// ---------------- Classifier: dense, 1 thread per node (round-11 proven) ----------------
__global__ __launch_bounds__(256) void k_cls(
    const float* __restrict__ emb, const float* __restrict__ Wc1, const float* __restrict__ bc1,
    const float* __restrict__ Wc2, const float* __restrict__ bc2, float* __restrict__ risk){
    int n = blockIdx.x * 256 + threadIdx.x;
    if (n >= N_NODES) return;
    const float* er = emb + (size_t)n * 16;
    float4 e0 = *(const float4*)(er);
    float4 e1 = *(const float4*)(er + 4);
    float4 e2 = *(const float4*)(er + 8);
    float4 e3 = *(const float4*)(er + 12);
    float ev[16] = {e0.x, e0.y, e0.z, e0.w, e1.x, e1.y, e1.z, e1.w,
                    e2.x, e2.y, e2.z, e2.w, e3.x, e3.y, e3.z, e3.w};
    float hid[8];
    #pragma unroll
    for (int j = 0; j < 8; j++) hid[j] = bc1[j];
    #pragma unroll
    for (int d = 0; d < 16; d++){
        float v = ev[d];
        #pragma unroll
        for (int j = 0; j < 8; j++) hid[j] = fmaf(v, Wc1[d * 8 + j], hid[j]);
    }
    float o = bc2[0];
    #pragma unroll
    for (int j = 0; j < 8; j++) o = fmaf(fmaxf(hid[j], 0.f), Wc2[j], o);
    risk[n] = 1.f / (1.f + __expf(-o));
}

extern "C" void kernel_launch(void* const* d_in, const int* in_sizes, int n_in,
                              void* d_out, int out_size, void* d_ws, size_t ws_size,
                              hipStream_t stream){
    const float* x    = (const float*)d_in[0];
    const int*   ei   = (const int*)d_in[1];
    const float* W1   = (const float*)d_in[2];
    const float* as1w = (const float*)d_in[3];
    const float* ad1w = (const float*)d_in[4];
    const float* b1   = (const float*)d_in[5];
    const float* W2   = (const float*)d_in[6];
    const float* as2w = (const float*)d_in[7];
    const float* ad2w = (const float*)d_in[8];
    const float* b2   = (const float*)d_in[9];
    const float* Wc1  = (const float*)d_in[10];
    const float* bc1  = (const float*)d_in[11];
    const float* Wc2  = (const float*)d_in[12];
    const float* bc2  = (const float*)d_in[13];
    float* out = (float*)d_out;
    const int* src = ei;
    const int* dst = ei + N_EDGES;

    float* ws   = (float*)d_ws;
    float* a_s2 = ws;                                   // N
    float* a_d2 = a_s2 + N_NODES;                       // N
    float* xa   = a_d2 + N_NODES;                       // N*8 (fp16-packed rows)
    float* xagg = xa + (size_t)N_NODES * 8;             // N*32
    float* dden = xagg + (size_t)N_NODES * 32;          // N*4
    __half* h2h = (__half*)(dden + (size_t)N_NODES * 4);// N*16 f16
    int* deg    = (int*)(h2h + (size_t)N_NODES * 16);   // N
    int* eslot  = deg + N_NODES;                        // N*64

    hipMemsetAsync(deg, 0, N_NODES * sizeof(int), stream);
    k_scatter_xa<<<NBLK_SC + NBLK_A, 256, 0, stream>>>(
        src, dst, deg, eslot, x, W1, as1w, ad1w, xa);
    k_agg1<<<N_NODES / 4, 256, 0, stream>>>(xa, deg, eslot, xagg, dden);
    k_epi<<<N_NODES / 16, 256, 0, stream>>>(
        xagg, dden, W1, W2, b1, as2w, ad2w, h2h, a_s2, a_d2);
    k_agg2<<<N_NODES / 4, 256, 0, stream>>>(h2h, a_s2, a_d2, deg, eslot, b2, out);
    k_cls<<<(N_NODES + 255) / 256, 256, 0, stream>>>(
        out, Wc1, bc1, Wc2, bc2, out + (size_t)N_NODES * 16);
}

// Round 15
// 238.258 us; speedup vs baseline: 1.3247x; 1.3247x over previous
//
#include <hip/hip_runtime.h>
#include <hip/hip_fp16.h>
#include <math.h>

#define N_NODES 100000
#define N_EDGES 1600000
#define F_IN 8
#define HID 32
#define HEADS 4
#define F1 128    // HEADS*HID
#define F2 16     // OUT
#define NB 391          // buckets of 256 nodes
#define NBLK_BIN 782    // edge-binning blocks of 2048 edges
#define EDGES_PER_BIN 2048
#define NBLK_A 391      // xa blocks of 256 nodes
#define BCAP 4864       // per-bucket capacity (mean 4092, sd ~64 -> 12 sigma)

__device__ __forceinline__ float leaky(float x){ return x > 0.f ? x : 0.2f * x; }
__device__ __forceinline__ float elu1(float x){ return x > 0.f ? x : __expf(x) - 1.f; }
__device__ __forceinline__ float half_of(float v, int hi){
    float2 f = __half22float2(*(__half2*)&v);
    return hi ? f.y : f.x;
}
__device__ __forceinline__ float2 h2f2(float v){ return __half22float2(*(__half2*)&v); }

// ---------------- Fused: edge binning (blocks 0..781) + xa build (rest) ----------------
// Round-14 lesson: direct per-edge scatter = 1.6M random 4B stores -> 64B
// write-allocate amplification (99 MB, ~137 us HBM-write-bound). The bucket
// binning below keeps writes LINE-LOCAL (block-batched runs per bucket, ~30 MB).
// xa16[n][8 dwords] = { x[0:8] as 4xhalf2, a_s1[0:4] as 2xhalf2, a_d1[0:4] as 2xhalf2 }
__global__ __launch_bounds__(256) void k_bin_attn(
    const int* __restrict__ src, const int* __restrict__ dst,
    int* __restrict__ bucketCnt, unsigned int* __restrict__ ebuf,
    const float* __restrict__ x, const float* __restrict__ W1,
    const float* __restrict__ as1w, const float* __restrict__ ad1w,
    float* __restrict__ xa){
    __shared__ float smem[1344];
    int t = threadIdx.x;
    if (blockIdx.x < NBLK_BIN){
        int* hist    = (int*)smem;
        int* basePos = hist + NB;
        int* cur     = basePos + NB;
        for (int j = t; j < NB; j += 256) hist[j] = 0;
        __syncthreads();
        int base = blockIdx.x * EDGES_PER_BIN;
        int dv[8];                         // register-cache dst (skip re-read in scatter pass)
        #pragma unroll
        for (int j = 0; j < 8; j++){
            int e = base + j * 256 + t;
            dv[j] = (e < N_EDGES) ? dst[e] : -1;
            if (dv[j] >= 0) atomicAdd(&hist[dv[j] >> 8], 1);
        }
        __syncthreads();
        for (int j = t; j < NB; j += 256){
            int h = hist[j];
            if (h) basePos[j] = atomicAdd(&bucketCnt[j], h);
            cur[j] = 0;
        }
        __syncthreads();
        #pragma unroll
        for (int j = 0; j < 8; j++){
            if (dv[j] >= 0){
                int e = base + j * 256 + t;
                int d = dv[j];
                int b = d >> 8;
                int off = atomicAdd(&cur[b], 1);
                ebuf[b * BCAP + basePos[b] + off] = ((unsigned)(d & 255) << 17) | (unsigned)src[e];
            }
        }
    } else {
        // ---- attention dots: c = W1·att (tiny), then fp16 xa row per node ----
        float* W1s  = smem;          // 1024
        float* atts = smem + 1024;   // 128
        float* attd = smem + 1152;   // 128
        float* cs   = smem + 1280;   // 32  (cs[h*8+m])
        float* cd   = smem + 1312;   // 32
        ((float4*)W1s)[t] = ((const float4*)W1)[t];
        if (t < 128){ atts[t] = as1w[t]; attd[t] = ad1w[t]; }
        __syncthreads();
        if (t < 64){
            int m = t & 7, h = (t >> 3) & 3;
            bool sel = t >= 32;
            const float* wrow = W1s + m * F1 + h * 32;
            const float* av   = (sel ? attd : atts) + h * 32;
            float s = 0.f;
            #pragma unroll
            for (int d = 0; d < 32; d++) s += wrow[d] * av[d];
            (sel ? cd : cs)[h * 8 + m] = s;
        }
        __syncthreads();
        int n = (blockIdx.x - NBLK_BIN) * 256 + t;
        if (n < N_NODES){
            float4 x0 = ((const float4*)x)[n * 2];
            float4 x1 = ((const float4*)x)[n * 2 + 1];
            float4 osv, odv;
            float* po = (float*)&osv;
            float* pd = (float*)&odv;
            #pragma unroll
            for (int h = 0; h < 4; h++){
                const float* c0 = cs + h * 8;
                const float* c1 = cd + h * 8;
                po[h] = x0.x*c0[0] + x0.y*c0[1] + x0.z*c0[2] + x0.w*c0[3]
                      + x1.x*c0[4] + x1.y*c0[5] + x1.z*c0[6] + x1.w*c0[7];
                pd[h] = x0.x*c1[0] + x0.y*c1[1] + x0.z*c1[2] + x0.w*c1[3]
                      + x1.x*c1[4] + x1.y*c1[5] + x1.z*c1[6] + x1.w*c1[7];
            }
            __half2 h8[8];
            h8[0] = __floats2half2_rn(x0.x, x0.y);
            h8[1] = __floats2half2_rn(x0.z, x0.w);
            h8[2] = __floats2half2_rn(x1.x, x1.y);
            h8[3] = __floats2half2_rn(x1.z, x1.w);
            h8[4] = __floats2half2_rn(osv.x, osv.y);
            h8[5] = __floats2half2_rn(osv.z, osv.w);
            h8[6] = __floats2half2_rn(odv.x, odv.y);
            h8[7] = __floats2half2_rn(odv.z, odv.w);
            float* px = xa + (size_t)n * 8;
            *(float4*)(px)     = *(float4*)(h8);
            *(float4*)(px + 4) = *(float4*)(h8 + 4);
        }
    }
}

// ---------------- CSR pass 2: one 512-thread block per bucket ----------------
__global__ __launch_bounds__(512) void k_local_csr(
    const int* __restrict__ bucketCnt, const unsigned int* __restrict__ ebuf,
    int* __restrict__ row_ptr, int* __restrict__ esrc){
    __shared__ int deg[256];
    __shared__ int scn[512];
    __shared__ int cntAll[NB];
    __shared__ unsigned int segs[BCAP];   // LDS cache of this bucket's edges (19.5 KB)
    int b = blockIdx.x, t = threadIdx.x;
    if (t < 256) deg[t] = 0;
    for (int j = t; j < NB; j += 512) cntAll[j] = bucketCnt[j];
    __syncthreads();
    // parallel bucket-prefix: sum cntAll[0..b) across all 512 threads
    int partial = 0;
    for (int j = t; j < b; j += 512) partial += cntAll[j];
    scn[t] = partial;
    __syncthreads();
    for (int off = 256; off > 0; off >>= 1){
        if (t < off) scn[t] += scn[t + off];
        __syncthreads();
    }
    int sbase = scn[0];
    int cnt = cntAll[b];
    __syncthreads();
    const unsigned int* seg = ebuf + b * BCAP;
    for (int i = t; i < cnt; i += 512){
        unsigned int e = seg[i];
        segs[i] = e;                      // cache for scatter pass (kills 2nd global read)
        atomicAdd(&deg[e >> 17], 1);
    }
    __syncthreads();
    // exclusive scan over the 256 per-node degrees (t<256 active; uniform barriers)
    int v = (t < 256) ? deg[t] : 0;
    if (t < 256) scn[t] = v;
    __syncthreads();
    for (int off = 1; off < 256; off <<= 1){
        int xx = (t < 256 && t >= off) ? scn[t - off] : 0;
        __syncthreads();
        if (t < 256) scn[t] += xx;
        __syncthreads();
    }
    if (t < 256){
        int excl = scn[t] - v;
        int start = sbase + excl;
        int n = b * 256 + t;
        if (n < N_NODES) row_ptr[n] = start;
        deg[t] = start;        // reuse as global cursor
    }
    if (b == NB - 1 && t == 0) row_ptr[N_NODES] = sbase + cnt;
    __syncthreads();
    for (int i = t; i < cnt; i += 512){
        unsigned int e = segs[i];
        int pos = atomicAdd(&deg[e >> 17], 1);
        esrc[pos] = (int)(e & 0x1FFFFu);
    }
}

// ---------------- Layer 1 aggregate: SHFL-FREE loop (round-15) ----------------
// 4 edge-groups (g) x 16 lanes. Lane (hd=l>>2, c=l&3) owns head hd, x-dims
// 2c..2c+1. Per edge: TWO INDEPENDENT 4B gathers off the same 32B row (x-pair
// dword c; logit dword 4+(hd>>1)) -- same cache line, issued back-to-back, no
// added chain (round-10 lesson), and ZERO ds_bpermute in the loop (round-12's
// 3 shfls/edge occupied the LDS pipe ~6cy each and dominated issue).
__global__ __launch_bounds__(256) void k_agg1(
    const float* __restrict__ xa, const int* __restrict__ row_ptr, const int* __restrict__ esrc,
    float* __restrict__ xagg, float* __restrict__ dden){
    int t = threadIdx.x;
    int wv = t >> 6, lane = t & 63;
    int n = blockIdx.x * 4 + wv;               // N divisible by 4
    int g = lane >> 4;                          // edge subgroup (0..3)
    int l = lane & 15;
    int hd = l >> 2;                            // head (0..3)
    int c  = l & 3;                             // x dword (dims 2c, 2c+1)
    int as_dw = 4 + (hd >> 1);                  // a_s1[hd] dword
    int ad_dw = 6 + (hd >> 1);                  // a_d1[hd] dword
    int hpar  = hd & 1;

    const float* rowN = xa + (size_t)n * 8;
    float adh = half_of(rowN[ad_dw], hpar);

    float den = 0.f, ac0 = 0.f, ac1 = 0.f;
    if (g == 0){
        // self-loop (softmax shift m=0; logits O(1), fp32 acc)
        float w = __expf(leaky(half_of(rowN[as_dw], hpar) + adh));
        den = w;
        float2 p = h2f2(rowN[c]);
        ac0 = w * p.x; ac1 = w * p.y;
    }
    int start = row_ptr[n], end = row_ptr[n + 1];
    int len = end - start;
    int chunk = (len + 3) >> 2;
    int i = start + g * chunk;
    int e = i + chunk; if (e > end) e = end;
    for (int base = i; base < e; base += 4){
        bool b1v = base + 1 < e, b2v = base + 2 < e, b3v = base + 3 < e;
        int s0 = esrc[base];
        int s1 = b1v ? esrc[base + 1] : s0;
        int s2 = b2v ? esrc[base + 2] : s0;
        int s3 = b3v ? esrc[base + 3] : s0;
        float xv0 = xa[(size_t)s0 * 8 + c];
        float av0 = xa[(size_t)s0 * 8 + as_dw];
        float xv1 = xa[(size_t)s1 * 8 + c];
        float av1 = xa[(size_t)s1 * 8 + as_dw];
        float xv2 = xa[(size_t)s2 * 8 + c];
        float av2 = xa[(size_t)s2 * 8 + as_dw];
        float xv3 = xa[(size_t)s3 * 8 + c];
        float av3 = xa[(size_t)s3 * 8 + as_dw];
        float w0 = __expf(leaky(half_of(av0, hpar) + adh));
        float w1 = b1v ? __expf(leaky(half_of(av1, hpar) + adh)) : 0.f;
        float w2 = b2v ? __expf(leaky(half_of(av2, hpar) + adh)) : 0.f;
        float w3 = b3v ? __expf(leaky(half_of(av3, hpar) + adh)) : 0.f;
        den += (w0 + w1) + (w2 + w3);
        float2 p;
        p = h2f2(xv0); ac0 = fmaf(w0, p.x, ac0); ac1 = fmaf(w0, p.y, ac1);
        p = h2f2(xv1); ac0 = fmaf(w1, p.x, ac0); ac1 = fmaf(w1, p.y, ac1);
        p = h2f2(xv2); ac0 = fmaf(w2, p.x, ac0); ac1 = fmaf(w2, p.y, ac1);
        p = h2f2(xv3); ac0 = fmaf(w3, p.x, ac0); ac1 = fmaf(w3, p.y, ac1);
    }
    // combine the four edge-groups (lanes xor16/xor32 share l)
    den += __shfl_xor(den, 16); den += __shfl_xor(den, 32);
    ac0 += __shfl_xor(ac0, 16); ac0 += __shfl_xor(ac0, 32);
    ac1 += __shfl_xor(ac1, 16); ac1 += __shfl_xor(ac1, 32);

    if (lane < 16){
        // xagg[n][hd*8 + 2c .. +1]: 16 lanes -> 128 B coalesced
        float2 o; o.x = ac0; o.y = ac1;
        *(float2*)(xagg + (size_t)n * 32 + 8 * hd + 2 * c) = o;
        if (c == 0) dden[(size_t)n * 4 + hd] = den;
    }
}

// ---------------- Dense epilogue (fp16-packed LDS, round-8 proven) ----------------
// hL1 = elu(xagg@W1/den + b1); h2 = hL1@W2. 16 nodes x 16 threads per block.
__global__ __launch_bounds__(256) void k_epi(
    const float* __restrict__ xagg, const float* __restrict__ dden,
    const float* __restrict__ W1, const float* __restrict__ W2,
    const float* __restrict__ b1, const float* __restrict__ as2w, const float* __restrict__ ad2w,
    __half* __restrict__ h2h, float* __restrict__ a_s2, float* __restrict__ a_d2){
    __shared__ __half2 W1h[F_IN * 64];   // 2 KB
    __shared__ __half2 W2t[F2 * 64];     // 4 KB, swizzled
    __shared__ __half2 hlsh[16 * 68];    // 4.25 KB
    int t = threadIdx.x;
    {
        // W1h: thread t covers W1 elems 4t..4t+3 -> m = t>>5, dim-pairs (2t)&63, +1
        float4 w1v = ((const float4*)W1)[t];
        int m = t >> 5, j = (2 * t) & 63;
        W1h[m * 64 + j]     = __floats2half2_rn(w1v.x, w1v.y);
        W1h[m * 64 + j + 1] = __floats2half2_rn(w1v.z, w1v.w);
        // W2t: transpose-scatter two float4s (one-time half-granular writes)
        #pragma unroll
        for (int hf = 0; hf < 2; hf++){
            int p = t + hf * 256;
            float4 wv = ((const float4*)W2)[p];
            int k = p >> 2, dbase = (p & 3) * 4;
            float vals[4] = {wv.x, wv.y, wv.z, wv.w};
            #pragma unroll
            for (int cq = 0; cq < 4; cq++){
                int dw = (dbase + cq) * 64 + (k >> 1);
                int sdw = dw ^ (((dw >> 6) & 7) << 2);
                ((__half*)W2t)[2 * sdw + (k & 1)] = __float2half(vals[cq]);
            }
        }
    }
    __syncthreads();

    int nn = t >> 4, q = t & 15;
    int n = blockIdx.x * 16 + nn;              // N divisible by 16
    int hd = q >> 2;

    // ---- phase 1: hL1 dims 8q..8q+7 ----
    const float* xg = xagg + (size_t)n * 32 + hd * 8;
    float4 xga = *(const float4*)(xg);
    float4 xgb = *(const float4*)(xg + 4);
    float invd = 1.f / dden[(size_t)n * 4 + hd];
    float xv[8] = {xga.x, xga.y, xga.z, xga.w, xgb.x, xgb.y, xgb.z, xgb.w};
    float pre[8] = {0,0,0,0,0,0,0,0};
    #pragma unroll
    for (int m = 0; m < 8; m++){
        float4 raw = *(const float4*)(W1h + m * 64 + 4 * q);   // conflict-free: q-consecutive
        const __half2* wp = (const __half2*)&raw;
        float xm = xv[m];
        float2 f0 = __half22float2(wp[0]);
        float2 f1 = __half22float2(wp[1]);
        float2 f2 = __half22float2(wp[2]);
        float2 f3 = __half22float2(wp[3]);
        pre[0] = fmaf(xm, f0.x, pre[0]); pre[1] = fmaf(xm, f0.y, pre[1]);
        pre[2] = fmaf(xm, f1.x, pre[2]); pre[3] = fmaf(xm, f1.y, pre[3]);
        pre[4] = fmaf(xm, f2.x, pre[4]); pre[5] = fmaf(xm, f2.y, pre[5]);
        pre[6] = fmaf(xm, f3.x, pre[6]); pre[7] = fmaf(xm, f3.y, pre[7]);
    }
    float4 ba = *(const float4*)(b1 + 8 * q);
    float4 bb = *(const float4*)(b1 + 8 * q + 4);
    __half2 hout[4];
    hout[0] = __floats2half2_rn(elu1(pre[0] * invd + ba.x), elu1(pre[1] * invd + ba.y));
    hout[1] = __floats2half2_rn(elu1(pre[2] * invd + ba.z), elu1(pre[3] * invd + ba.w));
    hout[2] = __floats2half2_rn(elu1(pre[4] * invd + bb.x), elu1(pre[5] * invd + bb.y));
    hout[3] = __floats2half2_rn(elu1(pre[6] * invd + bb.z), elu1(pre[7] * invd + bb.w));
    *(float4*)(hlsh + nn * 68 + 4 * q) = *(float4*)hout;
    __syncthreads();

    // ---- phase 2: h2[n][q] = hL1 . W2col(q), fp16 packed, f32 flush every 8 terms ----
    float dot = 0.f;
    #pragma unroll
    for (int ob = 0; ob < 8; ob++){
        __half2 acc2 = __float2half2_rn(0.f);
        #pragma unroll
        for (int kb = ob * 2; kb < ob * 2 + 2; kb++){
            float4 hr = *(const float4*)(hlsh + nn * 68 + 4 * kb);
            int dwb = 64 * q + 4 * kb;
            float4 wr = *(const float4*)(W2t + (dwb ^ (((dwb >> 6) & 7) << 2)));
            const __half2* hp  = (const __half2*)&hr;
            const __half2* wp2 = (const __half2*)&wr;
            acc2 = __hfma2(hp[0], wp2[0], acc2);
            acc2 = __hfma2(hp[1], wp2[1], acc2);
            acc2 = __hfma2(hp[2], wp2[2], acc2);
            acc2 = __hfma2(hp[3], wp2[3], acc2);
        }
        float2 fa = __half22float2(acc2);
        dot += fa.x + fa.y;
    }
    float ps = dot * as2w[q];
    float pd = dot * ad2w[q];
    #pragma unroll
    for (int off = 8; off >= 1; off >>= 1){
        ps += __shfl_down(ps, off, 16);
        pd += __shfl_down(pd, off, 16);
    }
    if (q == 0){ a_s2[n] = ps; a_d2[n] = pd; }
    h2h[(size_t)n * F2 + q] = __float2half(dot);
}

// ---------------- Layer 2 aggregate (round-8 proven loop; classifier in k_cls) ----------------
__global__ __launch_bounds__(256) void k_agg2(
    const __half* __restrict__ h2h, const float* __restrict__ a_s2, const float* __restrict__ a_d2,
    const int* __restrict__ row_ptr, const int* __restrict__ esrc,
    const float* __restrict__ b2, float* __restrict__ out){
    int t = threadIdx.x;
    int wv = t >> 6, lane = t & 63;
    int n = blockIdx.x * 4 + wv;       // N divisible by 4
    int g = lane >> 3;                 // edge subgroup (0..7)
    int l = lane & 7;                  // owns dims 2l, 2l+1
    float adn = a_d2[n];
    const __half* hb2 = h2h + 2 * l;

    float den = 0.f, acc0 = 0.f, acc1 = 0.f;
    if (g == 0){
        float w = __expf(leaky(a_s2[n] + adn));
        den = w;
        float2 f = __half22float2(*(const __half2*)(hb2 + ((unsigned)n << 4)));
        acc0 = w * f.x; acc1 = w * f.y;
    }
    int start = row_ptr[n], end = row_ptr[n + 1];
    int len = end - start;
    int chunk = (len + 7) >> 3;
    int i = start + g * chunk;
    int e = i + chunk; if (e > end) e = end;
    for (int base = i; base < e; base += 4){
        bool v1 = base + 1 < e, v2 = base + 2 < e, v3 = base + 3 < e;
        int s0 = esrc[base];
        int s1 = v1 ? esrc[base + 1] : s0;
        int s2 = v2 ? esrc[base + 2] : s0;
        int s3 = v3 ? esrc[base + 3] : s0;
        float a0 = a_s2[s0], a1 = a_s2[s1], a2 = a_s2[s2], a3 = a_s2[s3];
        __half2 p0 = *(const __half2*)(hb2 + ((unsigned)s0 << 4));
        __half2 p1 = *(const __half2*)(hb2 + ((unsigned)s1 << 4));
        __half2 p2 = *(const __half2*)(hb2 + ((unsigned)s2 << 4));
        __half2 p3 = *(const __half2*)(hb2 + ((unsigned)s3 << 4));
        float w0 = __expf(leaky(a0 + adn));
        float w1 = v1 ? __expf(leaky(a1 + adn)) : 0.f;
        float w2 = v2 ? __expf(leaky(a2 + adn)) : 0.f;
        float w3 = v3 ? __expf(leaky(a3 + adn)) : 0.f;
        den += (w0 + w1) + (w2 + w3);
        float2 f0 = __half22float2(p0), f1 = __half22float2(p1);
        float2 f2 = __half22float2(p2), f3 = __half22float2(p3);
        acc0 += w0 * f0.x + w1 * f1.x + w2 * f2.x + w3 * f3.x;
        acc1 += w0 * f0.y + w1 * f1.y + w2 * f2.y + w3 * f3.y;
    }
    #pragma unroll
    for (int off = 8; off <= 32; off <<= 1){
        den  += __shfl_xor(den, off);
        acc0 += __shfl_xor(acc0, off);
        acc1 += __shfl_xor(acc1, off);
    }
    if (g == 0){
        float inv = 1.f / (den + 1e-16f);
        float e0v = elu1(acc0 * inv + b2[2 * l]);
        float e1v = elu1(acc1 * inv + b2[2 * l + 1]);
        float2 ov; ov.x = e0v; ov.y = e1v;
        *(float2*)(out + (size_t)n * 16 + 2 * l) = ov;
    }
}

// ---------------- Classifier: dense, 1 thread per node (round-11 proven) ----------------
__global__ __launch_bounds__(256) void k_cls(
    const float* __restrict__ emb, const float* __restrict__ Wc1, const float* __restrict__ bc1,
    const float* __restrict__ Wc2, const float* __restrict__ bc2, float* __restrict__ risk){
    int n = blockIdx.x * 256 + threadIdx.x;
    if (n >= N_NODES) return;
    const float* er = emb + (size_t)n * 16;
    float4 e0 = *(const float4*)(er);
    float4 e1 = *(const float4*)(er + 4);
    float4 e2 = *(const float4*)(er + 8);
    float4 e3 = *(const float4*)(er + 12);
    float ev[16] = {e0.x, e0.y, e0.z, e0.w, e1.x, e1.y, e1.z, e1.w,
                    e2.x, e2.y, e2.z, e2.w, e3.x, e3.y, e3.z, e3.w};
    float hid[8];
    #pragma unroll
    for (int j = 0; j < 8; j++) hid[j] = bc1[j];
    #pragma unroll
    for (int d = 0; d < 16; d++){
        float v = ev[d];
        #pragma unroll
        for (int j = 0; j < 8; j++) hid[j] = fmaf(v, Wc1[d * 8 + j], hid[j]);
    }
    float o = bc2[0];
    #pragma unroll
    for (int j = 0; j < 8; j++) o = fmaf(fmaxf(hid[j], 0.f), Wc2[j], o);
    risk[n] = 1.f / (1.f + __expf(-o));
}

extern "C" void kernel_launch(void* const* d_in, const int* in_sizes, int n_in,
                              void* d_out, int out_size, void* d_ws, size_t ws_size,
                              hipStream_t stream){
    const float* x    = (const float*)d_in[0];
    const int*   ei   = (const int*)d_in[1];
    const float* W1   = (const float*)d_in[2];
    const float* as1w = (const float*)d_in[3];
    const float* ad1w = (const float*)d_in[4];
    const float* b1   = (const float*)d_in[5];
    const float* W2   = (const float*)d_in[6];
    const float* as2w = (const float*)d_in[7];
    const float* ad2w = (const float*)d_in[8];
    const float* b2   = (const float*)d_in[9];
    const float* Wc1  = (const float*)d_in[10];
    const float* bc1  = (const float*)d_in[11];
    const float* Wc2  = (const float*)d_in[12];
    const float* bc2  = (const float*)d_in[13];
    float* out = (float*)d_out;
    const int* src = ei;
    const int* dst = ei + N_EDGES;

    float* ws   = (float*)d_ws;
    float* a_s2 = ws;                                   // N
    float* a_d2 = a_s2 + N_NODES;                       // N
    float* xa   = a_d2 + N_NODES;                       // N*8 (fp16-packed rows)
    float* xagg = xa + (size_t)N_NODES * 8;             // N*32
    float* dden = xagg + (size_t)N_NODES * 32;          // N*4
    __half* h2h = (__half*)(dden + (size_t)N_NODES * 4);// N*16 f16
    int* bucketCnt = (int*)(h2h + (size_t)N_NODES * 16);// NB
    int* row_ptr  = bucketCnt + NB;                     // N+1
    int* esrc     = row_ptr + N_NODES + 1;              // E
    unsigned int* ebuf = (unsigned int*)(esrc + N_EDGES); // NB*BCAP

    hipMemsetAsync(bucketCnt, 0, NB * sizeof(int), stream);
    k_bin_attn<<<NBLK_BIN + NBLK_A, 256, 0, stream>>>(
        src, dst, bucketCnt, ebuf, x, W1, as1w, ad1w, xa);
    k_local_csr<<<NB, 512, 0, stream>>>(bucketCnt, ebuf, row_ptr, esrc);
    k_agg1<<<N_NODES / 4, 256, 0, stream>>>(xa, row_ptr, esrc, xagg, dden);
    k_epi<<<N_NODES / 16, 256, 0, stream>>>(
        xagg, dden, W1, W2, b1, as2w, ad2w, h2h, a_s2, a_d2);
    k_agg2<<<N_NODES / 4, 256, 0, stream>>>(h2h, a_s2, a_d2, row_ptr, esrc, b2, out);
    k_cls<<<(N_NODES + 255) / 256, 256, 0, stream>>>(
        out, Wc1, bc1, Wc2, bc2, out + (size_t)N_NODES * 16);
}

// Round 16
// 224.963 us; speedup vs baseline: 1.4030x; 1.0591x over previous
//
#include <hip/hip_runtime.h>
#include <hip/hip_fp16.h>
#include <math.h>

#define N_NODES 100000
#define N_EDGES 1600000
#define F_IN 8
#define HID 32
#define HEADS 4
#define F1 128    // HEADS*HID
#define F2 16     // OUT
#define NB 391          // buckets of 256 nodes
#define NBLK_BIN 391    // edge-binning blocks of 4096 edges (round-16: longer bucket
                        // runs -> half the partial-line write amplification vs 2048)
#define EDGES_PER_BIN 4096
#define NBLK_A 391      // xa blocks of 256 nodes
#define BCAP 4864       // per-bucket capacity (mean 4092, sd ~64 -> 12 sigma)

__device__ __forceinline__ float leaky(float x){ return x > 0.f ? x : 0.2f * x; }
__device__ __forceinline__ float elu1(float x){ return x > 0.f ? x : __expf(x) - 1.f; }
__device__ __forceinline__ float half_of(float v, int hi){
    float2 f = __half22float2(*(__half2*)&v);
    return hi ? f.y : f.x;
}
__device__ __forceinline__ float2 h2f2(float v){ return __half22float2(*(__half2*)&v); }

// ---------------- Fused: edge binning (blocks 0..390) + xa build (rest) ----------------
// Round-14 lesson: direct per-edge scatter = 64B write-allocate amplification
// (99 MB). Bucket binning keeps writes line-local; 4096 edges/block makes the
// mean per-bucket run 10.5 edges (42 B) so most runs dirty ONE line (~10 MB amp
// vs ~20 MB at 2048).
// xa16[n][8 dwords] = { x[0:8] as 4xhalf2, a_s1[0:4] as 2xhalf2, a_d1[0:4] as 2xhalf2 }
__global__ __launch_bounds__(256) void k_bin_attn(
    const int* __restrict__ src, const int* __restrict__ dst,
    int* __restrict__ bucketCnt, unsigned int* __restrict__ ebuf,
    const float* __restrict__ x, const float* __restrict__ W1,
    const float* __restrict__ as1w, const float* __restrict__ ad1w,
    float* __restrict__ xa){
    __shared__ float smem[1344];
    int t = threadIdx.x;
    if (blockIdx.x < NBLK_BIN){
        int* hist    = (int*)smem;
        int* basePos = hist + NB;
        int* cur     = basePos + NB;
        for (int j = t; j < NB; j += 256) hist[j] = 0;
        __syncthreads();
        int base = blockIdx.x * EDGES_PER_BIN;
        int dv[16];                        // register-cache dst (skip re-read in scatter pass)
        #pragma unroll
        for (int j = 0; j < 16; j++){
            int e = base + j * 256 + t;
            dv[j] = (e < N_EDGES) ? dst[e] : -1;
            if (dv[j] >= 0) atomicAdd(&hist[dv[j] >> 8], 1);
        }
        __syncthreads();
        for (int j = t; j < NB; j += 256){
            int h = hist[j];
            if (h) basePos[j] = atomicAdd(&bucketCnt[j], h);
            cur[j] = 0;
        }
        __syncthreads();
        #pragma unroll
        for (int j = 0; j < 16; j++){
            if (dv[j] >= 0){
                int e = base + j * 256 + t;
                int d = dv[j];
                int b = d >> 8;
                int off = atomicAdd(&cur[b], 1);
                ebuf[b * BCAP + basePos[b] + off] = ((unsigned)(d & 255) << 17) | (unsigned)src[e];
            }
        }
    } else {
        // ---- attention dots: c = W1·att (tiny), then fp16 xa row per node ----
        float* W1s  = smem;          // 1024
        float* atts = smem + 1024;   // 128
        float* attd = smem + 1152;   // 128
        float* cs   = smem + 1280;   // 32  (cs[h*8+m])
        float* cd   = smem + 1312;   // 32
        ((float4*)W1s)[t] = ((const float4*)W1)[t];
        if (t < 128){ atts[t] = as1w[t]; attd[t] = ad1w[t]; }
        __syncthreads();
        if (t < 64){
            int m = t & 7, h = (t >> 3) & 3;
            bool sel = t >= 32;
            const float* wrow = W1s + m * F1 + h * 32;
            const float* av   = (sel ? attd : atts) + h * 32;
            float s = 0.f;
            #pragma unroll
            for (int d = 0; d < 32; d++) s += wrow[d] * av[d];
            (sel ? cd : cs)[h * 8 + m] = s;
        }
        __syncthreads();
        int n = (blockIdx.x - NBLK_BIN) * 256 + t;
        if (n < N_NODES){
            float4 x0 = ((const float4*)x)[n * 2];
            float4 x1 = ((const float4*)x)[n * 2 + 1];
            float4 osv, odv;
            float* po = (float*)&osv;
            float* pd = (float*)&odv;
            #pragma unroll
            for (int h = 0; h < 4; h++){
                const float* c0 = cs + h * 8;
                const float* c1 = cd + h * 8;
                po[h] = x0.x*c0[0] + x0.y*c0[1] + x0.z*c0[2] + x0.w*c0[3]
                      + x1.x*c0[4] + x1.y*c0[5] + x1.z*c0[6] + x1.w*c0[7];
                pd[h] = x0.x*c1[0] + x0.y*c1[1] + x0.z*c1[2] + x0.w*c1[3]
                      + x1.x*c1[4] + x1.y*c1[5] + x1.z*c1[6] + x1.w*c1[7];
            }
            __half2 h8[8];
            h8[0] = __floats2half2_rn(x0.x, x0.y);
            h8[1] = __floats2half2_rn(x0.z, x0.w);
            h8[2] = __floats2half2_rn(x1.x, x1.y);
            h8[3] = __floats2half2_rn(x1.z, x1.w);
            h8[4] = __floats2half2_rn(osv.x, osv.y);
            h8[5] = __floats2half2_rn(osv.z, osv.w);
            h8[6] = __floats2half2_rn(odv.x, odv.y);
            h8[7] = __floats2half2_rn(odv.z, odv.w);
            float* px = xa + (size_t)n * 8;
            *(float4*)(px)     = *(float4*)(h8);
            *(float4*)(px + 4) = *(float4*)(h8 + 4);
        }
    }
}

// ---------------- CSR pass 2: one 512-thread block per bucket ----------------
__global__ __launch_bounds__(512) void k_local_csr(
    const int* __restrict__ bucketCnt, const unsigned int* __restrict__ ebuf,
    int* __restrict__ row_ptr, int* __restrict__ esrc){
    __shared__ int deg[256];
    __shared__ int scn[512];
    __shared__ int cntAll[NB];
    __shared__ unsigned int segs[BCAP];   // LDS cache of this bucket's edges (19.5 KB)
    int b = blockIdx.x, t = threadIdx.x;
    if (t < 256) deg[t] = 0;
    for (int j = t; j < NB; j += 512) cntAll[j] = bucketCnt[j];
    __syncthreads();
    // parallel bucket-prefix: sum cntAll[0..b) across all 512 threads
    int partial = 0;
    for (int j = t; j < b; j += 512) partial += cntAll[j];
    scn[t] = partial;
    __syncthreads();
    for (int off = 256; off > 0; off >>= 1){
        if (t < off) scn[t] += scn[t + off];
        __syncthreads();
    }
    int sbase = scn[0];
    int cnt = cntAll[b];
    __syncthreads();
    const unsigned int* seg = ebuf + b * BCAP;
    for (int i = t; i < cnt; i += 512){
        unsigned int e = seg[i];
        segs[i] = e;                      // cache for scatter pass (kills 2nd global read)
        atomicAdd(&deg[e >> 17], 1);
    }
    __syncthreads();
    // exclusive scan over the 256 per-node degrees (t<256 active; uniform barriers)
    int v = (t < 256) ? deg[t] : 0;
    if (t < 256) scn[t] = v;
    __syncthreads();
    for (int off = 1; off < 256; off <<= 1){
        int xx = (t < 256 && t >= off) ? scn[t - off] : 0;
        __syncthreads();
        if (t < 256) scn[t] += xx;
        __syncthreads();
    }
    if (t < 256){
        int excl = scn[t] - v;
        int start = sbase + excl;
        int n = b * 256 + t;
        if (n < N_NODES) row_ptr[n] = start;
        deg[t] = start;        // reuse as global cursor
    }
    if (b == NB - 1 && t == 0) row_ptr[N_NODES] = sbase + cnt;
    __syncthreads();
    for (int i = t; i < cnt; i += 512){
        unsigned int e = segs[i];
        int pos = atomicAdd(&deg[e >> 17], 1);
        esrc[pos] = (int)(e & 0x1FFFFu);
    }
}

// ---------------- Layer 1 aggregate (round-12 proven form, 44.1 us) ----------------
// 8 edge-groups (g) x 8 lanes (l); lane l loads dword l of the 32 B xa row
// (8 lanes = one full row, <=1 line/edge); head hd=l>>1, x-dims 4(l&1)..+3.
// 1 gather + 3 width-8 shfls per edge. Round-15 lesson: trading the shfls for a
// 2nd gather regresses (vmem issue is the binding resource, not the LDS pipe).
__global__ __launch_bounds__(256) void k_agg1(
    const float* __restrict__ xa, const int* __restrict__ row_ptr, const int* __restrict__ esrc,
    float* __restrict__ xagg, float* __restrict__ dden){
    int t = threadIdx.x;
    int wv = t >> 6, lane = t & 63;
    int n = blockIdx.x * 4 + wv;               // N divisible by 4
    int g = lane >> 3;                          // edge subgroup (0..7)
    int l = lane & 7;
    int hd = l >> 1;                            // head (0..3)
    int ha = 4 + (hd >> 1), hb = hd & 1;        // a_s1[hd] lives in dword ha, half hb
    int xd = 2 * (l & 1);                       // my x dwords: xd, xd+1

    float vn = xa[(size_t)n * 8 + l];
    float adh = half_of(__shfl(vn, ha + 2, 8), hb);   // a_d1[hd]: dword 6+(hd>>1)

    float den = 0.f, ac0 = 0.f, ac1 = 0.f, ac2 = 0.f, ac3 = 0.f;
    if (g == 0){
        // self-loop (softmax shift m=0; logits O(1), fp32 acc)
        float w = __expf(leaky(half_of(__shfl(vn, ha, 8), hb) + adh));
        den = w;
        float2 p01 = h2f2(__shfl(vn, xd, 8));
        float2 p23 = h2f2(__shfl(vn, xd + 1, 8));
        ac0 = w * p01.x; ac1 = w * p01.y; ac2 = w * p23.x; ac3 = w * p23.y;
    }
    int start = row_ptr[n], end = row_ptr[n + 1];
    int len = end - start;
    int chunk = (len + 7) >> 3;
    int i = start + g * chunk;
    int e = i + chunk; if (e > end) e = end;
    for (int base = i; base < e; base += 4){
        bool b1v = base + 1 < e, b2v = base + 2 < e, b3v = base + 3 < e;
        int s0 = esrc[base];
        int s1 = b1v ? esrc[base + 1] : s0;
        int s2 = b2v ? esrc[base + 2] : s0;
        int s3 = b3v ? esrc[base + 3] : s0;
        float v0 = xa[(size_t)s0 * 8 + l];
        float v1 = xa[(size_t)s1 * 8 + l];
        float v2 = xa[(size_t)s2 * 8 + l];
        float v3 = xa[(size_t)s3 * 8 + l];
        float w0 = __expf(leaky(half_of(__shfl(v0, ha, 8), hb) + adh));
        float w1 = b1v ? __expf(leaky(half_of(__shfl(v1, ha, 8), hb) + adh)) : 0.f;
        float w2 = b2v ? __expf(leaky(half_of(__shfl(v2, ha, 8), hb) + adh)) : 0.f;
        float w3 = b3v ? __expf(leaky(half_of(__shfl(v3, ha, 8), hb) + adh)) : 0.f;
        den += (w0 + w1) + (w2 + w3);
        float2 a01, a23;
        a01 = h2f2(__shfl(v0, xd, 8)); a23 = h2f2(__shfl(v0, xd + 1, 8));
        ac0 = fmaf(w0, a01.x, ac0); ac1 = fmaf(w0, a01.y, ac1);
        ac2 = fmaf(w0, a23.x, ac2); ac3 = fmaf(w0, a23.y, ac3);
        a01 = h2f2(__shfl(v1, xd, 8)); a23 = h2f2(__shfl(v1, xd + 1, 8));
        ac0 = fmaf(w1, a01.x, ac0); ac1 = fmaf(w1, a01.y, ac1);
        ac2 = fmaf(w1, a23.x, ac2); ac3 = fmaf(w1, a23.y, ac3);
        a01 = h2f2(__shfl(v2, xd, 8)); a23 = h2f2(__shfl(v2, xd + 1, 8));
        ac0 = fmaf(w2, a01.x, ac0); ac1 = fmaf(w2, a01.y, ac1);
        ac2 = fmaf(w2, a23.x, ac2); ac3 = fmaf(w2, a23.y, ac3);
        a01 = h2f2(__shfl(v3, xd, 8)); a23 = h2f2(__shfl(v3, xd + 1, 8));
        ac0 = fmaf(w3, a01.x, ac0); ac1 = fmaf(w3, a01.y, ac1);
        ac2 = fmaf(w3, a23.x, ac2); ac3 = fmaf(w3, a23.y, ac3);
    }
    // combine the eight edge-groups (lanes xor8/xor16/xor32 share l)
    den += __shfl_xor(den, 8); den += __shfl_xor(den, 16); den += __shfl_xor(den, 32);
    ac0 += __shfl_xor(ac0, 8); ac0 += __shfl_xor(ac0, 16); ac0 += __shfl_xor(ac0, 32);
    ac1 += __shfl_xor(ac1, 8); ac1 += __shfl_xor(ac1, 16); ac1 += __shfl_xor(ac1, 32);
    ac2 += __shfl_xor(ac2, 8); ac2 += __shfl_xor(ac2, 16); ac2 += __shfl_xor(ac2, 32);
    ac3 += __shfl_xor(ac3, 8); ac3 += __shfl_xor(ac3, 16); ac3 += __shfl_xor(ac3, 32);

    if (lane < 8){
        // xagg[n][hd*8 + (l&1)*4 ..+3] == xagg[n][4l..4l+3]: 8 lanes -> 128 B coalesced
        float4 o; o.x = ac0; o.y = ac1; o.z = ac2; o.w = ac3;
        *(float4*)(xagg + (size_t)n * 32 + 4 * l) = o;
        if (!(l & 1)) dden[(size_t)n * 4 + hd] = den;
    }
}

// ---------------- Dense epilogue (fp16-packed LDS, round-8 proven) ----------------
// hL1 = elu(xagg@W1/den + b1); h2 = hL1@W2. 16 nodes x 16 threads per block.
__global__ __launch_bounds__(256) void k_epi(
    const float* __restrict__ xagg, const float* __restrict__ dden,
    const float* __restrict__ W1, const float* __restrict__ W2,
    const float* __restrict__ b1, const float* __restrict__ as2w, const float* __restrict__ ad2w,
    __half* __restrict__ h2h, float* __restrict__ a_s2, float* __restrict__ a_d2){
    __shared__ __half2 W1h[F_IN * 64];   // 2 KB
    __shared__ __half2 W2t[F2 * 64];     // 4 KB, swizzled
    __shared__ __half2 hlsh[16 * 68];    // 4.25 KB
    int t = threadIdx.x;
    {
        // W1h: thread t covers W1 elems 4t..4t+3 -> m = t>>5, dim-pairs (2t)&63, +1
        float4 w1v = ((const float4*)W1)[t];
        int m = t >> 5, j = (2 * t) & 63;
        W1h[m * 64 + j]     = __floats2half2_rn(w1v.x, w1v.y);
        W1h[m * 64 + j + 1] = __floats2half2_rn(w1v.z, w1v.w);
        // W2t: transpose-scatter two float4s (one-time half-granular writes)
        #pragma unroll
        for (int hf = 0; hf < 2; hf++){
            int p = t + hf * 256;
            float4 wv = ((const float4*)W2)[p];
            int k = p >> 2, dbase = (p & 3) * 4;
            float vals[4] = {wv.x, wv.y, wv.z, wv.w};
            #pragma unroll
            for (int cq = 0; cq < 4; cq++){
                int dw = (dbase + cq) * 64 + (k >> 1);
                int sdw = dw ^ (((dw >> 6) & 7) << 2);
                ((__half*)W2t)[2 * sdw + (k & 1)] = __float2half(vals[cq]);
            }
        }
    }
    __syncthreads();

    int nn = t >> 4, q = t & 15;
    int n = blockIdx.x * 16 + nn;              // N divisible by 16
    int hd = q >> 2;

    // ---- phase 1: hL1 dims 8q..8q+7 ----
    const float* xg = xagg + (size_t)n * 32 + hd * 8;
    float4 xga = *(const float4*)(xg);
    float4 xgb = *(const float4*)(xg + 4);
    float invd = 1.f / dden[(size_t)n * 4 + hd];
    float xv[8] = {xga.x, xga.y, xga.z, xga.w, xgb.x, xgb.y, xgb.z, xgb.w};
    float pre[8] = {0,0,0,0,0,0,0,0};
    #pragma unroll
    for (int m = 0; m < 8; m++){
        float4 raw = *(const float4*)(W1h + m * 64 + 4 * q);   // conflict-free: q-consecutive
        const __half2* wp = (const __half2*)&raw;
        float xm = xv[m];
        float2 f0 = __half22float2(wp[0]);
        float2 f1 = __half22float2(wp[1]);
        float2 f2 = __half22float2(wp[2]);
        float2 f3 = __half22float2(wp[3]);
        pre[0] = fmaf(xm, f0.x, pre[0]); pre[1] = fmaf(xm, f0.y, pre[1]);
        pre[2] = fmaf(xm, f1.x, pre[2]); pre[3] = fmaf(xm, f1.y, pre[3]);
        pre[4] = fmaf(xm, f2.x, pre[4]); pre[5] = fmaf(xm, f2.y, pre[5]);
        pre[6] = fmaf(xm, f3.x, pre[6]); pre[7] = fmaf(xm, f3.y, pre[7]);
    }
    float4 ba = *(const float4*)(b1 + 8 * q);
    float4 bb = *(const float4*)(b1 + 8 * q + 4);
    __half2 hout[4];
    hout[0] = __floats2half2_rn(elu1(pre[0] * invd + ba.x), elu1(pre[1] * invd + ba.y));
    hout[1] = __floats2half2_rn(elu1(pre[2] * invd + ba.z), elu1(pre[3] * invd + ba.w));
    hout[2] = __floats2half2_rn(elu1(pre[4] * invd + bb.x), elu1(pre[5] * invd + bb.y));
    hout[3] = __floats2half2_rn(elu1(pre[6] * invd + bb.z), elu1(pre[7] * invd + bb.w));
    *(float4*)(hlsh + nn * 68 + 4 * q) = *(float4*)hout;
    __syncthreads();

    // ---- phase 2: h2[n][q] = hL1 . W2col(q), fp16 packed, f32 flush every 8 terms ----
    float dot = 0.f;
    #pragma unroll
    for (int ob = 0; ob < 8; ob++){
        __half2 acc2 = __float2half2_rn(0.f);
        #pragma unroll
        for (int kb = ob * 2; kb < ob * 2 + 2; kb++){
            float4 hr = *(const float4*)(hlsh + nn * 68 + 4 * kb);
            int dwb = 64 * q + 4 * kb;
            float4 wr = *(const float4*)(W2t + (dwb ^ (((dwb >> 6) & 7) << 2)));
            const __half2* hp  = (const __half2*)&hr;
            const __half2* wp2 = (const __half2*)&wr;
            acc2 = __hfma2(hp[0], wp2[0], acc2);
            acc2 = __hfma2(hp[1], wp2[1], acc2);
            acc2 = __hfma2(hp[2], wp2[2], acc2);
            acc2 = __hfma2(hp[3], wp2[3], acc2);
        }
        float2 fa = __half22float2(acc2);
        dot += fa.x + fa.y;
    }
    float ps = dot * as2w[q];
    float pd = dot * ad2w[q];
    #pragma unroll
    for (int off = 8; off >= 1; off >>= 1){
        ps += __shfl_down(ps, off, 16);
        pd += __shfl_down(pd, off, 16);
    }
    if (q == 0){ a_s2[n] = ps; a_d2[n] = pd; }
    h2h[(size_t)n * F2 + q] = __float2half(dot);
}

// ---------------- Layer 2 aggregate (round-8 proven loop; classifier in k_cls) ----------------
__global__ __launch_bounds__(256) void k_agg2(
    const __half* __restrict__ h2h, const float* __restrict__ a_s2, const float* __restrict__ a_d2,
    const int* __restrict__ row_ptr, const int* __restrict__ esrc,
    const float* __restrict__ b2, float* __restrict__ out){
    int t = threadIdx.x;
    int wv = t >> 6, lane = t & 63;
    int n = blockIdx.x * 4 + wv;       // N divisible by 4
    int g = lane >> 3;                 // edge subgroup (0..7)
    int l = lane & 7;                  // owns dims 2l, 2l+1
    float adn = a_d2[n];
    const __half* hb2 = h2h + 2 * l;

    float den = 0.f, acc0 = 0.f, acc1 = 0.f;
    if (g == 0){
        float w = __expf(leaky(a_s2[n] + adn));
        den = w;
        float2 f = __half22float2(*(const __half2*)(hb2 + ((unsigned)n << 4)));
        acc0 = w * f.x; acc1 = w * f.y;
    }
    int start = row_ptr[n], end = row_ptr[n + 1];
    int len = end - start;
    int chunk = (len + 7) >> 3;
    int i = start + g * chunk;
    int e = i + chunk; if (e > end) e = end;
    for (int base = i; base < e; base += 4){
        bool v1 = base + 1 < e, v2 = base + 2 < e, v3 = base + 3 < e;
        int s0 = esrc[base];
        int s1 = v1 ? esrc[base + 1] : s0;
        int s2 = v2 ? esrc[base + 2] : s0;
        int s3 = v3 ? esrc[base + 3] : s0;
        float a0 = a_s2[s0], a1 = a_s2[s1], a2 = a_s2[s2], a3 = a_s2[s3];
        __half2 p0 = *(const __half2*)(hb2 + ((unsigned)s0 << 4));
        __half2 p1 = *(const __half2*)(hb2 + ((unsigned)s1 << 4));
        __half2 p2 = *(const __half2*)(hb2 + ((unsigned)s2 << 4));
        __half2 p3 = *(const __half2*)(hb2 + ((unsigned)s3 << 4));
        float w0 = __expf(leaky(a0 + adn));
        float w1 = v1 ? __expf(leaky(a1 + adn)) : 0.f;
        float w2 = v2 ? __expf(leaky(a2 + adn)) : 0.f;
        float w3 = v3 ? __expf(leaky(a3 + adn)) : 0.f;
        den += (w0 + w1) + (w2 + w3);
        float2 f0 = __half22float2(p0), f1 = __half22float2(p1);
        float2 f2 = __half22float2(p2), f3 = __half22float2(p3);
        acc0 += w0 * f0.x + w1 * f1.x + w2 * f2.x + w3 * f3.x;
        acc1 += w0 * f0.y + w1 * f1.y + w2 * f2.y + w3 * f3.y;
    }
    #pragma unroll
    for (int off = 8; off <= 32; off <<= 1){
        den  += __shfl_xor(den, off);
        acc0 += __shfl_xor(acc0, off);
        acc1 += __shfl_xor(acc1, off);
    }
    if (g == 0){
        float inv = 1.f / (den + 1e-16f);
        float e0v = elu1(acc0 * inv + b2[2 * l]);
        float e1v = elu1(acc1 * inv + b2[2 * l + 1]);
        float2 ov; ov.x = e0v; ov.y = e1v;
        *(float2*)(out + (size_t)n * 16 + 2 * l) = ov;
    }
}

// ---------------- Classifier: dense, 1 thread per node (round-11 proven) ----------------
__global__ __launch_bounds__(256) void k_cls(
    const float* __restrict__ emb, const float* __restrict__ Wc1, const float* __restrict__ bc1,
    const float* __restrict__ Wc2, const float* __restrict__ bc2, float* __restrict__ risk){
    int n = blockIdx.x * 256 + threadIdx.x;
    if (n >= N_NODES) return;
    const float* er = emb + (size_t)n * 16;
    float4 e0 = *(const float4*)(er);
    float4 e1 = *(const float4*)(er + 4);
    float4 e2 = *(const float4*)(er + 8);
    float4 e3 = *(const float4*)(er + 12);
    float ev[16] = {e0.x, e0.y, e0.z, e0.w, e1.x, e1.y, e1.z, e1.w,
                    e2.x, e2.y, e2.z, e2.w, e3.x, e3.y, e3.z, e3.w};
    float hid[8];
    #pragma unroll
    for (int j = 0; j < 8; j++) hid[j] = bc1[j];
    #pragma unroll
    for (int d = 0; d < 16; d++){
        float v = ev[d];
        #pragma unroll
        for (int j = 0; j < 8; j++) hid[j] = fmaf(v, Wc1[d * 8 + j], hid[j]);
    }
    float o = bc2[0];
    #pragma unroll
    for (int j = 0; j < 8; j++) o = fmaf(fmaxf(hid[j], 0.f), Wc2[j], o);
    risk[n] = 1.f / (1.f + __expf(-o));
}

extern "C" void kernel_launch(void* const* d_in, const int* in_sizes, int n_in,
                              void* d_out, int out_size, void* d_ws, size_t ws_size,
                              hipStream_t stream){
    const float* x    = (const float*)d_in[0];
    const int*   ei   = (const int*)d_in[1];
    const float* W1   = (const float*)d_in[2];
    const float* as1w = (const float*)d_in[3];
    const float* ad1w = (const float*)d_in[4];
    const float* b1   = (const float*)d_in[5];
    const float* W2   = (const float*)d_in[6];
    const float* as2w = (const float*)d_in[7];
    const float* ad2w = (const float*)d_in[8];
    const float* b2   = (const float*)d_in[9];
    const float* Wc1  = (const float*)d_in[10];
    const float* bc1  = (const float*)d_in[11];
    const float* Wc2  = (const float*)d_in[12];
    const float* bc2  = (const float*)d_in[13];
    float* out = (float*)d_out;
    const int* src = ei;
    const int* dst = ei + N_EDGES;

    float* ws   = (float*)d_ws;
    float* a_s2 = ws;                                   // N
    float* a_d2 = a_s2 + N_NODES;                       // N
    float* xa   = a_d2 + N_NODES;                       // N*8 (fp16-packed rows)
    float* xagg = xa + (size_t)N_NODES * 8;             // N*32
    float* dden = xagg + (size_t)N_NODES * 32;          // N*4
    __half* h2h = (__half*)(dden + (size_t)N_NODES * 4);// N*16 f16
    int* bucketCnt = (int*)(h2h + (size_t)N_NODES * 16);// NB
    int* row_ptr  = bucketCnt + NB;                     // N+1
    int* esrc     = row_ptr + N_NODES + 1;              // E
    unsigned int* ebuf = (unsigned int*)(esrc + N_EDGES); // NB*BCAP

    hipMemsetAsync(bucketCnt, 0, NB * sizeof(int), stream);
    k_bin_attn<<<NBLK_BIN + NBLK_A, 256, 0, stream>>>(
        src, dst, bucketCnt, ebuf, x, W1, as1w, ad1w, xa);
    k_local_csr<<<NB, 512, 0, stream>>>(bucketCnt, ebuf, row_ptr, esrc);
    k_agg1<<<N_NODES / 4, 256, 0, stream>>>(xa, row_ptr, esrc, xagg, dden);
    k_epi<<<N_NODES / 16, 256, 0, stream>>>(
        xagg, dden, W1, W2, b1, as2w, ad2w, h2h, a_s2, a_d2);
    k_agg2<<<N_NODES / 4, 256, 0, stream>>>(h2h, a_s2, a_d2, row_ptr, esrc, b2, out);
    k_cls<<<(N_NODES + 255) / 256, 256, 0, stream>>>(
        out, Wc1, bc1, Wc2, bc2, out + (size_t)N_NODES * 16);
}

// Round 17
// 212.537 us; speedup vs baseline: 1.4850x; 1.0585x over previous
//
#include <hip/hip_runtime.h>
#include <hip/hip_fp16.h>
#include <math.h>

#define N_NODES 100000
#define N_EDGES 1600000
#define F_IN 8
#define HID 32
#define HEADS 4
#define F1 128    // HEADS*HID
#define F2 16     // OUT
#define NB 391          // buckets of 256 nodes
#define NBLK_BIN 391    // edge-binning blocks of 4096 edges (round-16 proven)
#define EDGES_PER_BIN 4096
#define NBLK_A 391      // xa blocks of 256 nodes
#define BCAP 4864       // per-bucket capacity (mean 4092, sd ~64 -> 12 sigma)
#define KSLOT 64        // per-node slot capacity (Poisson(16): P(>64) ~ 0)

__device__ __forceinline__ float leaky(float x){ return x > 0.f ? x : 0.2f * x; }
__device__ __forceinline__ float elu1(float x){ return x > 0.f ? x : __expf(x) - 1.f; }
__device__ __forceinline__ float half_of(float v, int hi){
    float2 f = __half22float2(*(__half2*)&v);
    return hi ? f.y : f.x;
}
__device__ __forceinline__ float2 h2f2(float v){ return __half22float2(*(__half2*)&v); }

// ---------------- Fused: edge binning (blocks 0..390) + xa build (rest) ----------------
// (round-16 proven: 4096 edges/block keeps bucket runs line-local, ~10 MB amp)
// xa16[n][8 dwords] = { x[0:8] as 4xhalf2, a_s1[0:4] as 2xhalf2, a_d1[0:4] as 2xhalf2 }
__global__ __launch_bounds__(256) void k_bin_attn(
    const int* __restrict__ src, const int* __restrict__ dst,
    int* __restrict__ bucketCnt, unsigned int* __restrict__ ebuf,
    const float* __restrict__ x, const float* __restrict__ W1,
    const float* __restrict__ as1w, const float* __restrict__ ad1w,
    float* __restrict__ xa){
    __shared__ float smem[1344];
    int t = threadIdx.x;
    if (blockIdx.x < NBLK_BIN){
        int* hist    = (int*)smem;
        int* basePos = hist + NB;
        int* cur     = basePos + NB;
        for (int j = t; j < NB; j += 256) hist[j] = 0;
        __syncthreads();
        int base = blockIdx.x * EDGES_PER_BIN;
        int dv[16];                        // register-cache dst (skip re-read in scatter pass)
        #pragma unroll
        for (int j = 0; j < 16; j++){
            int e = base + j * 256 + t;
            dv[j] = (e < N_EDGES) ? dst[e] : -1;
            if (dv[j] >= 0) atomicAdd(&hist[dv[j] >> 8], 1);
        }
        __syncthreads();
        for (int j = t; j < NB; j += 256){
            int h = hist[j];
            if (h) basePos[j] = atomicAdd(&bucketCnt[j], h);
            cur[j] = 0;
        }
        __syncthreads();
        #pragma unroll
        for (int j = 0; j < 16; j++){
            if (dv[j] >= 0){
                int e = base + j * 256 + t;
                int d = dv[j];
                int b = d >> 8;
                int off = atomicAdd(&cur[b], 1);
                ebuf[b * BCAP + basePos[b] + off] = ((unsigned)(d & 255) << 17) | (unsigned)src[e];
            }
        }
    } else {
        // ---- attention dots: c = W1·att (tiny), then fp16 xa row per node ----
        float* W1s  = smem;          // 1024
        float* atts = smem + 1024;   // 128
        float* attd = smem + 1152;   // 128
        float* cs   = smem + 1280;   // 32  (cs[h*8+m])
        float* cd   = smem + 1312;   // 32
        ((float4*)W1s)[t] = ((const float4*)W1)[t];
        if (t < 128){ atts[t] = as1w[t]; attd[t] = ad1w[t]; }
        __syncthreads();
        if (t < 64){
            int m = t & 7, h = (t >> 3) & 3;
            bool sel = t >= 32;
            const float* wrow = W1s + m * F1 + h * 32;
            const float* av   = (sel ? attd : atts) + h * 32;
            float s = 0.f;
            #pragma unroll
            for (int d = 0; d < 32; d++) s += wrow[d] * av[d];
            (sel ? cd : cs)[h * 8 + m] = s;
        }
        __syncthreads();
        int n = (blockIdx.x - NBLK_BIN) * 256 + t;
        if (n < N_NODES){
            float4 x0 = ((const float4*)x)[n * 2];
            float4 x1 = ((const float4*)x)[n * 2 + 1];
            float4 osv, odv;
            float* po = (float*)&osv;
            float* pd = (float*)&odv;
            #pragma unroll
            for (int h = 0; h < 4; h++){
                const float* c0 = cs + h * 8;
                const float* c1 = cd + h * 8;
                po[h] = x0.x*c0[0] + x0.y*c0[1] + x0.z*c0[2] + x0.w*c0[3]
                      + x1.x*c0[4] + x1.y*c0[5] + x1.z*c0[6] + x1.w*c0[7];
                pd[h] = x0.x*c1[0] + x0.y*c1[1] + x0.z*c1[2] + x0.w*c1[3]
                      + x1.x*c1[4] + x1.y*c1[5] + x1.z*c1[6] + x1.w*c1[7];
            }
            __half2 h8[8];
            h8[0] = __floats2half2_rn(x0.x, x0.y);
            h8[1] = __floats2half2_rn(x0.z, x0.w);
            h8[2] = __floats2half2_rn(x1.x, x1.y);
            h8[3] = __floats2half2_rn(x1.z, x1.w);
            h8[4] = __floats2half2_rn(osv.x, osv.y);
            h8[5] = __floats2half2_rn(osv.z, osv.w);
            h8[6] = __floats2half2_rn(odv.x, odv.y);
            h8[7] = __floats2half2_rn(odv.z, odv.w);
            float* px = xa + (size_t)n * 8;
            *(float4*)(px)     = *(float4*)(h8);
            *(float4*)(px + 4) = *(float4*)(h8 + 4);
        }
    }
}

// ---------------- Slot build: one 512-thread block per bucket ----------------
// Round-17: writes per-node FIXED-STRIDE slots eslot[n][64] instead of packed
// CSR -- agg kernels then compute slot ADDRESSES with zero loads, removing one
// serial L2 link (row_ptr -> esrc -> xa becomes eslot || deg -> xa). No
// cross-bucket prefix and no node exclusive-scan needed (both phases deleted).
// Writes stay line-local (per-node slots contiguous; LDS-staged like before).
__global__ __launch_bounds__(512) void k_slot_csr(
    const int* __restrict__ bucketCnt, const unsigned int* __restrict__ ebuf,
    int* __restrict__ deg, int* __restrict__ eslot){
    __shared__ int dloc[256];
    __shared__ unsigned int segs[BCAP];   // LDS cache of this bucket's edges (19.5 KB)
    int b = blockIdx.x, t = threadIdx.x;
    if (t < 256) dloc[t] = 0;
    __syncthreads();
    int cnt = bucketCnt[b];
    const unsigned int* seg = ebuf + b * BCAP;
    for (int i = t; i < cnt; i += 512){
        unsigned int e = seg[i];
        segs[i] = e;                      // cache for scatter pass (kills 2nd global read)
        atomicAdd(&dloc[e >> 17], 1);
    }
    __syncthreads();
    if (t < 256){
        int n = b * 256 + t;
        if (n < N_NODES) deg[n] = dloc[t];
        dloc[t] = 0;                      // reuse as per-node cursor
    }
    __syncthreads();
    size_t nb0 = (size_t)b << 8;          // first node of bucket
    for (int i = t; i < cnt; i += 512){
        unsigned int e = segs[i];
        int ln = e >> 17;
        int pos = atomicAdd(&dloc[ln], 1);
        if (pos < KSLOT) eslot[((nb0 + ln) << 6) + pos] = (int)(e & 0x1FFFFu);
    }
}

// ---------------- Layer 1 aggregate: fixed-slot edges, depth-2 load chain ----------------
// 8 edge-groups (g) x 8 lanes (l); lane l loads dword l of the 32 B xa row;
// head hd=l>>1, x-dims 4(l&1)..+3; 1 gather + 3 width-8 shfls per edge
// (round-15 lesson: do NOT trade shfls for extra gathers).
// Group g owns strided slots {g, g+8, g+16, g+24} (+{32..56} iff deg>32, P~1e-4):
// slot loads issue IMMEDIATELY (addresses need no loads), deg in parallel;
// validity masks applied after deg returns; invalid slots clamp to idx 0, w=0.
__global__ __launch_bounds__(256) void k_agg1(
    const float* __restrict__ xa, const int* __restrict__ deg, const int* __restrict__ eslot,
    float* __restrict__ xagg, float* __restrict__ dden){
    int t = threadIdx.x;
    int wv = t >> 6, lane = t & 63;
    int n = blockIdx.x * 4 + wv;               // N divisible by 4
    int g = lane >> 3;                          // edge subgroup (0..7)
    int l = lane & 7;
    int hd = l >> 1;                            // head (0..3)
    int ha = 4 + (hd >> 1), hb = hd & 1;        // a_s1[hd] lives in dword ha, half hb
    int xd = 2 * (l & 1);                       // my x dwords: xd, xd+1

    // issue all independent loads up front: slot batch + deg + own row
    const int* eb = eslot + ((size_t)n << 6);
    int e0 = eb[g], e1 = eb[g + 8], e2 = eb[g + 16], e3 = eb[g + 24];
    int len = deg[n];
    float vn = xa[(size_t)n * 8 + l];
    if (len > KSLOT) len = KSLOT;

    float adh = half_of(__shfl(vn, ha + 2, 8), hb);   // a_d1[hd]: dword 6+(hd>>1)

    float den = 0.f, ac0 = 0.f, ac1 = 0.f, ac2 = 0.f, ac3 = 0.f;
    if (g == 0){
        // self-loop (softmax shift m=0; logits O(1), fp32 acc)
        float w = __expf(leaky(half_of(__shfl(vn, ha, 8), hb) + adh));
        den = w;
        float2 p01 = h2f2(__shfl(vn, xd, 8));
        float2 p23 = h2f2(__shfl(vn, xd + 1, 8));
        ac0 = w * p01.x; ac1 = w * p01.y; ac2 = w * p23.x; ac3 = w * p23.y;
    }
    bool v0 = g < len, v1 = g + 8 < len, v2 = g + 16 < len, v3 = g + 24 < len;
    int s0 = v0 ? e0 : 0;
    int s1 = v1 ? e1 : s0;
    int s2 = v2 ? e2 : s0;
    int s3 = v3 ? e3 : s0;
    {
        float q0 = xa[(size_t)s0 * 8 + l];
        float q1 = xa[(size_t)s1 * 8 + l];
        float q2 = xa[(size_t)s2 * 8 + l];
        float q3 = xa[(size_t)s3 * 8 + l];
        float w0 = v0 ? __expf(leaky(half_of(__shfl(q0, ha, 8), hb) + adh)) : 0.f;
        float w1 = v1 ? __expf(leaky(half_of(__shfl(q1, ha, 8), hb) + adh)) : 0.f;
        float w2 = v2 ? __expf(leaky(half_of(__shfl(q2, ha, 8), hb) + adh)) : 0.f;
        float w3 = v3 ? __expf(leaky(half_of(__shfl(q3, ha, 8), hb) + adh)) : 0.f;
        den += (w0 + w1) + (w2 + w3);
        float2 a01, a23;
        a01 = h2f2(__shfl(q0, xd, 8)); a23 = h2f2(__shfl(q0, xd + 1, 8));
        ac0 = fmaf(w0, a01.x, ac0); ac1 = fmaf(w0, a01.y, ac1);
        ac2 = fmaf(w0, a23.x, ac2); ac3 = fmaf(w0, a23.y, ac3);
        a01 = h2f2(__shfl(q1, xd, 8)); a23 = h2f2(__shfl(q1, xd + 1, 8));
        ac0 = fmaf(w1, a01.x, ac0); ac1 = fmaf(w1, a01.y, ac1);
        ac2 = fmaf(w1, a23.x, ac2); ac3 = fmaf(w1, a23.y, ac3);
        a01 = h2f2(__shfl(q2, xd, 8)); a23 = h2f2(__shfl(q2, xd + 1, 8));
        ac0 = fmaf(w2, a01.x, ac0); ac1 = fmaf(w2, a01.y, ac1);
        ac2 = fmaf(w2, a23.x, ac2); ac3 = fmaf(w2, a23.y, ac3);
        a01 = h2f2(__shfl(q3, xd, 8)); a23 = h2f2(__shfl(q3, xd + 1, 8));
        ac0 = fmaf(w3, a01.x, ac0); ac1 = fmaf(w3, a01.y, ac1);
        ac2 = fmaf(w3, a23.x, ac2); ac3 = fmaf(w3, a23.y, ac3);
    }
    if (len > 32){   // rare tail (P(deg>32) ~ 1e-4), wave-uniform branch
        int f0 = eb[g + 32], f1 = eb[g + 40], f2 = eb[g + 48], f3 = eb[g + 56];
        bool u0 = g + 32 < len, u1 = g + 40 < len, u2 = g + 48 < len, u3 = g + 56 < len;
        int r0 = u0 ? f0 : 0;
        int r1 = u1 ? f1 : r0;
        int r2 = u2 ? f2 : r0;
        int r3 = u3 ? f3 : r0;
        float q0 = xa[(size_t)r0 * 8 + l];
        float q1 = xa[(size_t)r1 * 8 + l];
        float q2 = xa[(size_t)r2 * 8 + l];
        float q3 = xa[(size_t)r3 * 8 + l];
        float w0 = u0 ? __expf(leaky(half_of(__shfl(q0, ha, 8), hb) + adh)) : 0.f;
        float w1 = u1 ? __expf(leaky(half_of(__shfl(q1, ha, 8), hb) + adh)) : 0.f;
        float w2 = u2 ? __expf(leaky(half_of(__shfl(q2, ha, 8), hb) + adh)) : 0.f;
        float w3 = u3 ? __expf(leaky(half_of(__shfl(q3, ha, 8), hb) + adh)) : 0.f;
        den += (w0 + w1) + (w2 + w3);
        float2 a01, a23;
        a01 = h2f2(__shfl(q0, xd, 8)); a23 = h2f2(__shfl(q0, xd + 1, 8));
        ac0 = fmaf(w0, a01.x, ac0); ac1 = fmaf(w0, a01.y, ac1);
        ac2 = fmaf(w0, a23.x, ac2); ac3 = fmaf(w0, a23.y, ac3);
        a01 = h2f2(__shfl(q1, xd, 8)); a23 = h2f2(__shfl(q1, xd + 1, 8));
        ac0 = fmaf(w1, a01.x, ac0); ac1 = fmaf(w1, a01.y, ac1);
        ac2 = fmaf(w1, a23.x, ac2); ac3 = fmaf(w1, a23.y, ac3);
        a01 = h2f2(__shfl(q2, xd, 8)); a23 = h2f2(__shfl(q2, xd + 1, 8));
        ac0 = fmaf(w2, a01.x, ac0); ac1 = fmaf(w2, a01.y, ac1);
        ac2 = fmaf(w2, a23.x, ac2); ac3 = fmaf(w2, a23.y, ac3);
        a01 = h2f2(__shfl(q3, xd, 8)); a23 = h2f2(__shfl(q3, xd + 1, 8));
        ac0 = fmaf(w3, a01.x, ac0); ac1 = fmaf(w3, a01.y, ac1);
        ac2 = fmaf(w3, a23.x, ac2); ac3 = fmaf(w3, a23.y, ac3);
    }
    // combine the eight edge-groups (lanes xor8/xor16/xor32 share l)
    den += __shfl_xor(den, 8); den += __shfl_xor(den, 16); den += __shfl_xor(den, 32);
    ac0 += __shfl_xor(ac0, 8); ac0 += __shfl_xor(ac0, 16); ac0 += __shfl_xor(ac0, 32);
    ac1 += __shfl_xor(ac1, 8); ac1 += __shfl_xor(ac1, 16); ac1 += __shfl_xor(ac1, 32);
    ac2 += __shfl_xor(ac2, 8); ac2 += __shfl_xor(ac2, 16); ac2 += __shfl_xor(ac2, 32);
    ac3 += __shfl_xor(ac3, 8); ac3 += __shfl_xor(ac3, 16); ac3 += __shfl_xor(ac3, 32);

    if (lane < 8){
        // xagg[n][hd*8 + (l&1)*4 ..+3] == xagg[n][4l..4l+3]: 8 lanes -> 128 B coalesced
        float4 o; o.x = ac0; o.y = ac1; o.z = ac2; o.w = ac3;
        *(float4*)(xagg + (size_t)n * 32 + 4 * l) = o;
        if (!(l & 1)) dden[(size_t)n * 4 + hd] = den;
    }
}

// ---------------- Dense epilogue (fp16-packed LDS, round-8 proven) ----------------
// hL1 = elu(xagg@W1/den + b1); h2 = hL1@W2. 16 nodes x 16 threads per block.
__global__ __launch_bounds__(256) void k_epi(
    const float* __restrict__ xagg, const float* __restrict__ dden,
    const float* __restrict__ W1, const float* __restrict__ W2,
    const float* __restrict__ b1, const float* __restrict__ as2w, const float* __restrict__ ad2w,
    __half* __restrict__ h2h, float* __restrict__ a_s2, float* __restrict__ a_d2){
    __shared__ __half2 W1h[F_IN * 64];   // 2 KB
    __shared__ __half2 W2t[F2 * 64];     // 4 KB, swizzled
    __shared__ __half2 hlsh[16 * 68];    // 4.25 KB
    int t = threadIdx.x;
    {
        // W1h: thread t covers W1 elems 4t..4t+3 -> m = t>>5, dim-pairs (2t)&63, +1
        float4 w1v = ((const float4*)W1)[t];
        int m = t >> 5, j = (2 * t) & 63;
        W1h[m * 64 + j]     = __floats2half2_rn(w1v.x, w1v.y);
        W1h[m * 64 + j + 1] = __floats2half2_rn(w1v.z, w1v.w);
        // W2t: transpose-scatter two float4s (one-time half-granular writes)
        #pragma unroll
        for (int hf = 0; hf < 2; hf++){
            int p = t + hf * 256;
            float4 wv = ((const float4*)W2)[p];
            int k = p >> 2, dbase = (p & 3) * 4;
            float vals[4] = {wv.x, wv.y, wv.z, wv.w};
            #pragma unroll
            for (int cq = 0; cq < 4; cq++){
                int dw = (dbase + cq) * 64 + (k >> 1);
                int sdw = dw ^ (((dw >> 6) & 7) << 2);
                ((__half*)W2t)[2 * sdw + (k & 1)] = __float2half(vals[cq]);
            }
        }
    }
    __syncthreads();

    int nn = t >> 4, q = t & 15;
    int n = blockIdx.x * 16 + nn;              // N divisible by 16
    int hd = q >> 2;

    // ---- phase 1: hL1 dims 8q..8q+7 ----
    const float* xg = xagg + (size_t)n * 32 + hd * 8;
    float4 xga = *(const float4*)(xg);
    float4 xgb = *(const float4*)(xg + 4);
    float invd = 1.f / dden[(size_t)n * 4 + hd];
    float xv[8] = {xga.x, xga.y, xga.z, xga.w, xgb.x, xgb.y, xgb.z, xgb.w};
    float pre[8] = {0,0,0,0,0,0,0,0};
    #pragma unroll
    for (int m = 0; m < 8; m++){
        float4 raw = *(const float4*)(W1h + m * 64 + 4 * q);   // conflict-free: q-consecutive
        const __half2* wp = (const __half2*)&raw;
        float xm = xv[m];
        float2 f0 = __half22float2(wp[0]);
        float2 f1 = __half22float2(wp[1]);
        float2 f2 = __half22float2(wp[2]);
        float2 f3 = __half22float2(wp[3]);
        pre[0] = fmaf(xm, f0.x, pre[0]); pre[1] = fmaf(xm, f0.y, pre[1]);
        pre[2] = fmaf(xm, f1.x, pre[2]); pre[3] = fmaf(xm, f1.y, pre[3]);
        pre[4] = fmaf(xm, f2.x, pre[4]); pre[5] = fmaf(xm, f2.y, pre[5]);
        pre[6] = fmaf(xm, f3.x, pre[6]); pre[7] = fmaf(xm, f3.y, pre[7]);
    }
    float4 ba = *(const float4*)(b1 + 8 * q);
    float4 bb = *(const float4*)(b1 + 8 * q + 4);
    __half2 hout[4];
    hout[0] = __floats2half2_rn(elu1(pre[0] * invd + ba.x), elu1(pre[1] * invd + ba.y));
    hout[1] = __floats2half2_rn(elu1(pre[2] * invd + ba.z), elu1(pre[3] * invd + ba.w));
    hout[2] = __floats2half2_rn(elu1(pre[4] * invd + bb.x), elu1(pre[5] * invd + bb.y));
    hout[3] = __floats2half2_rn(elu1(pre[6] * invd + bb.z), elu1(pre[7] * invd + bb.w));
    *(float4*)(hlsh + nn * 68 + 4 * q) = *(float4*)hout;
    __syncthreads();

    // ---- phase 2: h2[n][q] = hL1 . W2col(q), fp16 packed, f32 flush every 8 terms ----
    float dot = 0.f;
    #pragma unroll
    for (int ob = 0; ob < 8; ob++){
        __half2 acc2 = __float2half2_rn(0.f);
        #pragma unroll
        for (int kb = ob * 2; kb < ob * 2 + 2; kb++){
            float4 hr = *(const float4*)(hlsh + nn * 68 + 4 * kb);
            int dwb = 64 * q + 4 * kb;
            float4 wr = *(const float4*)(W2t + (dwb ^ (((dwb >> 6) & 7) << 2)));
            const __half2* hp  = (const __half2*)&hr;
            const __half2* wp2 = (const __half2*)&wr;
            acc2 = __hfma2(hp[0], wp2[0], acc2);
            acc2 = __hfma2(hp[1], wp2[1], acc2);
            acc2 = __hfma2(hp[2], wp2[2], acc2);
            acc2 = __hfma2(hp[3], wp2[3], acc2);
        }
        float2 fa = __half22float2(acc2);
        dot += fa.x + fa.y;
    }
    float ps = dot * as2w[q];
    float pd = dot * ad2w[q];
    #pragma unroll
    for (int off = 8; off >= 1; off >>= 1){
        ps += __shfl_down(ps, off, 16);
        pd += __shfl_down(pd, off, 16);
    }
    if (q == 0){ a_s2[n] = ps; a_d2[n] = pd; }
    h2h[(size_t)n * F2 + q] = __float2half(dot);
}

// ---------------- Layer 2 aggregate: fixed-slot edges (round-8 math) ----------------
__global__ __launch_bounds__(256) void k_agg2(
    const __half* __restrict__ h2h, const float* __restrict__ a_s2, const float* __restrict__ a_d2,
    const int* __restrict__ deg, const int* __restrict__ eslot,
    const float* __restrict__ b2, float* __restrict__ out){
    int t = threadIdx.x;
    int wv = t >> 6, lane = t & 63;
    int n = blockIdx.x * 4 + wv;       // N divisible by 4
    int g = lane >> 3;                 // edge subgroup (0..7)
    int l = lane & 7;                  // owns dims 2l, 2l+1
    const __half* hb2 = h2h + 2 * l;

    // issue independent loads up front: slot batch + deg + own scalars
    const int* eb = eslot + ((size_t)n << 6);
    int e0 = eb[g], e1 = eb[g + 8], e2 = eb[g + 16], e3 = eb[g + 24];
    int len = deg[n];
    float adn = a_d2[n];
    if (len > KSLOT) len = KSLOT;

    float den = 0.f, acc0 = 0.f, acc1 = 0.f;
    if (g == 0){
        float w = __expf(leaky(a_s2[n] + adn));
        den = w;
        float2 f = __half22float2(*(const __half2*)(hb2 + ((unsigned)n << 4)));
        acc0 = w * f.x; acc1 = w * f.y;
    }
    bool v0 = g < len, v1 = g + 8 < len, v2 = g + 16 < len, v3 = g + 24 < len;
    int s0 = v0 ? e0 : 0;
    int s1 = v1 ? e1 : s0;
    int s2 = v2 ? e2 : s0;
    int s3 = v3 ? e3 : s0;
    {
        float a0 = a_s2[s0], a1 = a_s2[s1], a2 = a_s2[s2], a3 = a_s2[s3];
        __half2 p0 = *(const __half2*)(hb2 + ((unsigned)s0 << 4));
        __half2 p1 = *(const __half2*)(hb2 + ((unsigned)s1 << 4));
        __half2 p2 = *(const __half2*)(hb2 + ((unsigned)s2 << 4));
        __half2 p3 = *(const __half2*)(hb2 + ((unsigned)s3 << 4));
        float w0 = v0 ? __expf(leaky(a0 + adn)) : 0.f;
        float w1 = v1 ? __expf(leaky(a1 + adn)) : 0.f;
        float w2 = v2 ? __expf(leaky(a2 + adn)) : 0.f;
        float w3 = v3 ? __expf(leaky(a3 + adn)) : 0.f;
        den += (w0 + w1) + (w2 + w3);
        float2 f0 = __half22float2(p0), f1 = __half22float2(p1);
        float2 f2 = __half22float2(p2), f3 = __half22float2(p3);
        acc0 += w0 * f0.x + w1 * f1.x + w2 * f2.x + w3 * f3.x;
        acc1 += w0 * f0.y + w1 * f1.y + w2 * f2.y + w3 * f3.y;
    }
    if (len > 32){   // rare tail
        int f0i = eb[g + 32], f1i = eb[g + 40], f2i = eb[g + 48], f3i = eb[g + 56];
        bool u0 = g + 32 < len, u1 = g + 40 < len, u2 = g + 48 < len, u3 = g + 56 < len;
        int r0 = u0 ? f0i : 0;
        int r1 = u1 ? f1i : r0;
        int r2 = u2 ? f2i : r0;
        int r3 = u3 ? f3i : r0;
        float a0 = a_s2[r0], a1 = a_s2[r1], a2 = a_s2[r2], a3 = a_s2[r3];
        __half2 p0 = *(const __half2*)(hb2 + ((unsigned)r0 << 4));
        __half2 p1 = *(const __half2*)(hb2 + ((unsigned)r1 << 4));
        __half2 p2 = *(const __half2*)(hb2 + ((unsigned)r2 << 4));
        __half2 p3 = *(const __half2*)(hb2 + ((unsigned)r3 << 4));
        float w0 = u0 ? __expf(leaky(a0 + adn)) : 0.f;
        float w1 = u1 ? __expf(leaky(a1 + adn)) : 0.f;
        float w2 = u2 ? __expf(leaky(a2 + adn)) : 0.f;
        float w3 = u3 ? __expf(leaky(a3 + adn)) : 0.f;
        den += (w0 + w1) + (w2 + w3);
        float2 f0 = __half22float2(p0), f1 = __half22float2(p1);
        float2 f2 = __half22float2(p2), f3 = __half22float2(p3);
        acc0 += w0 * f0.x + w1 * f1.x + w2 * f2.x + w3 * f3.x;
        acc1 += w0 * f0.y + w1 * f1.y + w2 * f2.y + w3 * f3.y;
    }
    #pragma unroll
    for (int off = 8; off <= 32; off <<= 1){
        den  += __shfl_xor(den, off);
        acc0 += __shfl_xor(acc0, off);
        acc1 += __shfl_xor(acc1, off);
    }
    if (g == 0){
        float inv = 1.f / (den + 1e-16f);
        float e0v = elu1(acc0 * inv + b2[2 * l]);
        float e1v = elu1(acc1 * inv + b2[2 * l + 1]);
        float2 ov; ov.x = e0v; ov.y = e1v;
        *(float2*)(out + (size_t)n * 16 + 2 * l) = ov;
    }
}

// ---------------- Classifier: dense, 1 thread per node (round-11 proven) ----------------
__global__ __launch_bounds__(256) void k_cls(
    const float* __restrict__ emb, const float* __restrict__ Wc1, const float* __restrict__ bc1,
    const float* __restrict__ Wc2, const float* __restrict__ bc2, float* __restrict__ risk){
    int n = blockIdx.x * 256 + threadIdx.x;
    if (n >= N_NODES) return;
    const float* er = emb + (size_t)n * 16;
    float4 e0 = *(const float4*)(er);
    float4 e1 = *(const float4*)(er + 4);
    float4 e2 = *(const float4*)(er + 8);
    float4 e3 = *(const float4*)(er + 12);
    float ev[16] = {e0.x, e0.y, e0.z, e0.w, e1.x, e1.y, e1.z, e1.w,
                    e2.x, e2.y, e2.z, e2.w, e3.x, e3.y, e3.z, e3.w};
    float hid[8];
    #pragma unroll
    for (int j = 0; j < 8; j++) hid[j] = bc1[j];
    #pragma unroll
    for (int d = 0; d < 16; d++){
        float v = ev[d];
        #pragma unroll
        for (int j = 0; j < 8; j++) hid[j] = fmaf(v, Wc1[d * 8 + j], hid[j]);
    }
    float o = bc2[0];
    #pragma unroll
    for (int j = 0; j < 8; j++) o = fmaf(fmaxf(hid[j], 0.f), Wc2[j], o);
    risk[n] = 1.f / (1.f + __expf(-o));
}

extern "C" void kernel_launch(void* const* d_in, const int* in_sizes, int n_in,
                              void* d_out, int out_size, void* d_ws, size_t ws_size,
                              hipStream_t stream){
    const float* x    = (const float*)d_in[0];
    const int*   ei   = (const int*)d_in[1];
    const float* W1   = (const float*)d_in[2];
    const float* as1w = (const float*)d_in[3];
    const float* ad1w = (const float*)d_in[4];
    const float* b1   = (const float*)d_in[5];
    const float* W2   = (const float*)d_in[6];
    const float* as2w = (const float*)d_in[7];
    const float* ad2w = (const float*)d_in[8];
    const float* b2   = (const float*)d_in[9];
    const float* Wc1  = (const float*)d_in[10];
    const float* bc1  = (const float*)d_in[11];
    const float* Wc2  = (const float*)d_in[12];
    const float* bc2  = (const float*)d_in[13];
    float* out = (float*)d_out;
    const int* src = ei;
    const int* dst = ei + N_EDGES;

    float* ws   = (float*)d_ws;
    float* a_s2 = ws;                                   // N
    float* a_d2 = a_s2 + N_NODES;                       // N
    float* xa   = a_d2 + N_NODES;                       // N*8 (fp16-packed rows)
    float* xagg = xa + (size_t)N_NODES * 8;             // N*32
    float* dden = xagg + (size_t)N_NODES * 32;          // N*4
    __half* h2h = (__half*)(dden + (size_t)N_NODES * 4);// N*16 f16
    int* bucketCnt = (int*)(h2h + (size_t)N_NODES * 16);// NB
    int* deg    = bucketCnt + NB + 1;                   // N (keep 8B align downstream)
    int* eslot  = deg + N_NODES;                        // N*64
    unsigned int* ebuf = (unsigned int*)(eslot + (size_t)N_NODES * KSLOT); // NB*BCAP

    hipMemsetAsync(bucketCnt, 0, NB * sizeof(int), stream);
    k_bin_attn<<<NBLK_BIN + NBLK_A, 256, 0, stream>>>(
        src, dst, bucketCnt, ebuf, x, W1, as1w, ad1w, xa);
    k_slot_csr<<<NB, 512, 0, stream>>>(bucketCnt, ebuf, deg, eslot);
    k_agg1<<<N_NODES / 4, 256, 0, stream>>>(xa, deg, eslot, xagg, dden);
    k_epi<<<N_NODES / 16, 256, 0, stream>>>(
        xagg, dden, W1, W2, b1, as2w, ad2w, h2h, a_s2, a_d2);
    k_agg2<<<N_NODES / 4, 256, 0, stream>>>(h2h, a_s2, a_d2, deg, eslot, b2, out);
    k_cls<<<(N_NODES + 255) / 256, 256, 0, stream>>>(
        out, Wc1, bc1, Wc2, bc2, out + (size_t)N_NODES * 16);
}